// Round 4
// baseline (2118.863 us; speedup 1.0000x reference)
//
#include <hip/hip_runtime.h>

#define B_ 4
#define N_ 40000
#define E_ 240000
#define NB_SCAN ((N_ + 255) / 256)   // 157 scan blocks

typedef unsigned short u16;
typedef unsigned int u32;
typedef __attribute__((ext_vector_type(8))) short bf16x8;
typedef __attribute__((ext_vector_type(4))) float f32x4;

__device__ __forceinline__ float b2f(u16 h) {
    u32 u = ((u32)h) << 16;
    return __uint_as_float(u);
}
__device__ __forceinline__ u16 f2b(float f) {
    u32 u = __float_as_uint(f);
    u32 r = (u + 0x7fffu + ((u >> 16) & 1u)) >> 16;
    return (u16)r;
}
__device__ __forceinline__ float4 f4_zero() { return make_float4(0.f, 0.f, 0.f, 0.f); }

// ---------------- first linear: x = x_in @ w_first + b_first (bf16 out, 8 c/thread) ----------------
__global__ __launch_bounds__(256) void first_linear_kern(
    const float* __restrict__ x_in, const float* __restrict__ w,
    const float* __restrict__ bias, u16* __restrict__ xout, int M)
{
    __shared__ float sw[6 * 128];
    __shared__ float sb[128];
    int t = threadIdx.x;
    for (int i = t; i < 768; i += 256) sw[i] = w[i];
    if (t < 128) sb[t] = bias[t];
    __syncthreads();
    int idx = blockIdx.x * 256 + t;   // = row*16 + cg
    int row = idx >> 4;
    int cg = (idx & 15) * 8;
    if (row >= M) return;
    const float* xr = x_in + (size_t)row * 6;
    float xv[6];
#pragma unroll
    for (int j = 0; j < 6; j++) xv[j] = xr[j];
    float acc[8];
#pragma unroll
    for (int i = 0; i < 8; i++) acc[i] = sb[cg + i];
#pragma unroll
    for (int j = 0; j < 6; j++)
#pragma unroll
        for (int i = 0; i < 8; i++) acc[i] += xv[j] * sw[j * 128 + cg + i];
    ushort4 h0, h1;
    h0.x = f2b(acc[0]); h0.y = f2b(acc[1]); h0.z = f2b(acc[2]); h0.w = f2b(acc[3]);
    h1.x = f2b(acc[4]); h1.y = f2b(acc[5]); h1.z = f2b(acc[6]); h1.w = f2b(acc[7]);
    uint4 pk;
    pk.x = (u32)h0.x | ((u32)h0.y << 16);
    pk.y = (u32)h0.z | ((u32)h0.w << 16);
    pk.z = (u32)h1.x | ((u32)h1.y << 16);
    pk.w = (u32)h1.z | ((u32)h1.w << 16);
    *(uint4*)(xout + (size_t)row * 128 + cg) = pk;
}

// ------------- weight pack: dst[n][k] = bf16(src[k][n]), per block i = blockIdx.z -------------
__global__ __launch_bounds__(256) void pack_w_kern(
    const float* __restrict__ src, u16* __restrict__ dst, int K)
{
    int i = blockIdx.z;
    src += (size_t)i * K * 128;
    dst += (size_t)i * K * 128;
    int idx = blockIdx.x * 256 + threadIdx.x;  // = n*K + k
    int n = idx / K;
    int k = idx % K;
    dst[idx] = f2b(src[(size_t)k * 128 + n]);
}

// ------------- rotation weight pack: WR1[n][k256] = [Are; -Aim]^T, WR2 = [Are; Aim]^T -------------
__global__ __launch_bounds__(256) void pack_rot_kern(
    const float* __restrict__ Are, const float* __restrict__ Aim,
    u16* __restrict__ WR1, u16* __restrict__ WR2)
{
    int i = blockIdx.z;
    const float* are = Are + (size_t)i * 16384;
    const float* aim = Aim + (size_t)i * 16384;
    int idx = blockIdx.x * 256 + threadIdx.x;  // 0..32767 = n*256 + k
    int n = idx >> 8;
    int k = idx & 255;
    float v1, v2;
    if (k < 128) { float a = are[(size_t)k * 128 + n]; v1 = a; v2 = a; }
    else         { float a = aim[(size_t)(k - 128) * 128 + n]; v1 = -a; v2 = a; }
    WR1[(size_t)i * 32768 + idx] = f2b(v1);
    WR2[(size_t)i * 32768 + idx] = f2b(v2);
}

// ------------- CSR build: histogram -> 3-phase parallel scan -> scatter idx -> gather vals -------------
__global__ __launch_bounds__(256) void hist_kern(const int* __restrict__ rows, int* count)
{
    int e = blockIdx.x * 256 + threadIdx.x;
    if (e < E_) atomicAdd(&count[rows[e]], 1);
}

// inclusive scan across a 256-thread block (4 waves, shfl-based)
__device__ __forceinline__ int block_incl_scan_256(int v, int t)
{
    __shared__ int wsum[4];
    int lane = t & 63;
    int wid = t >> 6;
    int x = v;
#pragma unroll
    for (int off = 1; off < 64; off <<= 1) {
        int y = __shfl_up(x, off);
        if (lane >= off) x += y;
    }
    if (lane == 63) wsum[wid] = x;
    __syncthreads();
    if (t == 0) {
        int s = 0;
#pragma unroll
        for (int i = 0; i < 4; i++) { int tm = wsum[i]; wsum[i] = s; s += tm; }
    }
    __syncthreads();
    return x + wsum[wid];
}

// phase 1: per-block exclusive scan of counts -> rowptr (partial), block totals
__global__ __launch_bounds__(256) void scan1_kern(
    const int* __restrict__ count, int* __restrict__ excl_out,
    int* __restrict__ blockTotals)
{
    int t = threadIdx.x;
    int g = blockIdx.x * 256 + t;
    int v = (g < N_) ? count[g] : 0;
    int incl = block_incl_scan_256(v, t);
    if (g < N_) excl_out[g] = incl - v;
    if (t == 255) blockTotals[blockIdx.x] = incl;
}

// phase 2: single-block scan of 157 block totals -> exclusive block offsets + grand total
__global__ __launch_bounds__(256) void scan2_kern(
    const int* __restrict__ blockTotals, int* __restrict__ blockOffs,
    int* __restrict__ totalOut)
{
    int t = threadIdx.x;
    int v = (t < NB_SCAN) ? blockTotals[t] : 0;
    int incl = block_incl_scan_256(v, t);
    if (t < NB_SCAN) blockOffs[t] = incl - v;
    if (t == 255) *totalOut = incl;   // = E_, written to rowptr[N_]
}

// phase 3: add block offsets; materialize rowptr + nextp cursors
__global__ __launch_bounds__(256) void scan3_kern(
    int* __restrict__ rowptr, int* __restrict__ nextp,
    const int* __restrict__ blockOffs)
{
    int t = threadIdx.x;
    int g = blockIdx.x * 256 + t;
    if (g >= N_) return;
    int v = rowptr[g] + blockOffs[blockIdx.x];
    rowptr[g] = v;
    nextp[g] = v;
}

// scatter only indices (2 scattered u32 writes per edge)
__global__ __launch_bounds__(256) void scatter_idx_kern(
    const int* __restrict__ rows, const int* __restrict__ cols,
    int* nextp, int* __restrict__ scols, int* __restrict__ sperm)
{
    int e = blockIdx.x * 256 + threadIdx.x;
    if (e >= E_) return;
    int r = rows[e];
    int pos = atomicAdd(&nextp[r], 1);
    scols[pos] = cols[e];
    sperm[pos] = e;
}

// gather values: coalesced writes, L2-cached random reads
__global__ __launch_bounds__(256) void gather_vals_kern(
    const int* __restrict__ sperm,
    const float* __restrict__ gvx, const float* __restrict__ gvy,
    float* __restrict__ svx, float* __restrict__ svy)
{
    int pos = blockIdx.x * 256 + threadIdx.x;
    if (pos >= E_) return;
    int e = sperm[pos];
#pragma unroll
    for (int b = 0; b < B_; b++) {
        svx[(size_t)b * E_ + pos] = gvx[(size_t)b * E_ + e];
        svy[(size_t)b * E_ + pos] = gvy[(size_t)b * E_ + e];
    }
}

// ------------- spectral projection stage 1: MFMA over transposed LDS tiles -------------
// partials[b][pb][k][c] = sum over this block's n-stripe of evecs[n][k]*(x[n][c]*mass[n])
// evecs split hi/lo bf16 (effectively f32-exact); x*mass rounded to bf16 once.
__global__ __launch_bounds__(256) void spec_stage1_mfma_kern(
    const u16* __restrict__ x, const float* __restrict__ mass,
    const float* __restrict__ evecs, float* __restrict__ partials)
{
    // [out=128][n=32 + pad 8] bf16; row stride 80 B (16B-aligned rows, bank-uniform)
    __shared__ __align__(16) u16 sEVh[128][40];
    __shared__ __align__(16) u16 sEVl[128][40];
    __shared__ __align__(16) u16 sXM[128][40];
    int b = blockIdx.y;
    int pb = blockIdx.x;
    const u16* xb = x + (size_t)b * N_ * 128;
    const float* mb = mass + (size_t)b * N_;
    const float* eb = evecs + (size_t)b * N_ * 128;
    float* dst = partials + ((size_t)b * 128 + pb) * 16384;

    int t = threadIdx.x;
    int wv = t >> 6;
    int lane = t & 63;
    int quad = lane >> 4;
    int r16 = lane & 15;
    int kb = wv * 32;          // this wave's 32 output k-rows
    int kc = (t & 63) * 2;     // column pair this thread stages (k for ev, c for xm)
    int nh = wv;               // this thread's 8-n subrange within the 32-n chunk

    f32x4 acc[2][8];
#pragma unroll
    for (int i = 0; i < 2; i++)
#pragma unroll
        for (int j = 0; j < 8; j++) acc[i][j] = (f32x4){0.f, 0.f, 0.f, 0.f};

    for (int ch = pb; ch < N_ / 32; ch += 128) {
        int nbase = ch * 32 + nh * 8;

        // ---- load 2 columns x 8 n, pack transposed bf16 tiles in registers ----
        float4 m0 = *(const float4*)(mb + nbase);
        float4 m1 = *(const float4*)(mb + nbase + 4);
        float mm[8] = {m0.x, m0.y, m0.z, m0.w, m1.x, m1.y, m1.z, m1.w};
        u32 eh0[4], eh1[4], el0[4], el1[4], xq0[4], xq1[4];
#pragma unroll
        for (int jp = 0; jp < 4; jp++) {
            eh0[jp] = 0; eh1[jp] = 0; el0[jp] = 0;
            el1[jp] = 0; xq0[jp] = 0; xq1[jp] = 0;
        }
#pragma unroll
        for (int j = 0; j < 8; j++) {
            float2 e = *(const float2*)(eb + (size_t)(nbase + j) * 128 + kc);
            u32 xw = *(const u32*)(xb + (size_t)(nbase + j) * 128 + kc);
            u16 h0 = f2b(e.x);
            u16 h1 = f2b(e.y);
            u16 l0 = f2b(e.x - b2f(h0));
            u16 l1 = f2b(e.y - b2f(h1));
            u16 q0 = f2b(b2f((u16)(xw & 0xffffu)) * mm[j]);
            u16 q1 = f2b(b2f((u16)(xw >> 16)) * mm[j]);
            int sh = (j & 1) * 16;
            int jp = j >> 1;
            eh0[jp] |= ((u32)h0) << sh; eh1[jp] |= ((u32)h1) << sh;
            el0[jp] |= ((u32)l0) << sh; el1[jp] |= ((u32)l1) << sh;
            xq0[jp] |= ((u32)q0) << sh; xq1[jp] |= ((u32)q1) << sh;
        }
        __syncthreads();   // previous chunk's fragment reads complete
        *(uint4*)&sEVh[kc][nh * 8]     = make_uint4(eh0[0], eh0[1], eh0[2], eh0[3]);
        *(uint4*)&sEVh[kc + 1][nh * 8] = make_uint4(eh1[0], eh1[1], eh1[2], eh1[3]);
        *(uint4*)&sEVl[kc][nh * 8]     = make_uint4(el0[0], el0[1], el0[2], el0[3]);
        *(uint4*)&sEVl[kc + 1][nh * 8] = make_uint4(el1[0], el1[1], el1[2], el1[3]);
        *(uint4*)&sXM[kc][nh * 8]      = make_uint4(xq0[0], xq0[1], xq0[2], xq0[3]);
        *(uint4*)&sXM[kc + 1][nh * 8]  = make_uint4(xq1[0], xq1[1], xq1[2], xq1[3]);
        __syncthreads();

        // ---- MFMA: D[k][c] += ev^T(hi+lo) @ xm, contraction = 32 n ----
        bf16x8 ah0 = *(const bf16x8*)&sEVh[kb + r16][quad * 8];
        bf16x8 ah1 = *(const bf16x8*)&sEVh[kb + 16 + r16][quad * 8];
        bf16x8 al0 = *(const bf16x8*)&sEVl[kb + r16][quad * 8];
        bf16x8 al1 = *(const bf16x8*)&sEVl[kb + 16 + r16][quad * 8];
#pragma unroll
        for (int nt = 0; nt < 8; nt++) {
            bf16x8 bx = *(const bf16x8*)&sXM[nt * 16 + r16][quad * 8];
            acc[0][nt] = __builtin_amdgcn_mfma_f32_16x16x32_bf16(ah0, bx, acc[0][nt], 0, 0, 0);
            acc[1][nt] = __builtin_amdgcn_mfma_f32_16x16x32_bf16(ah1, bx, acc[1][nt], 0, 0, 0);
            acc[0][nt] = __builtin_amdgcn_mfma_f32_16x16x32_bf16(al0, bx, acc[0][nt], 0, 0, 0);
            acc[1][nt] = __builtin_amdgcn_mfma_f32_16x16x32_bf16(al1, bx, acc[1][nt], 0, 0, 0);
        }
    }

    // epilogue: D[row=quad*4+reg][col=r16] per 16x16 tile
#pragma unroll
    for (int mt = 0; mt < 2; mt++)
#pragma unroll
        for (int nt = 0; nt < 8; nt++)
#pragma unroll
            for (int reg = 0; reg < 4; reg++) {
                int kk = kb + mt * 16 + quad * 4 + reg;
                int cc = nt * 16 + r16;
                dst[(size_t)kk * 128 + cc] = acc[mt][nt][reg];
            }
}

// ------------- stage 2 + coefficients, TRANSPOSED bf16 out: ys_t[b][c][k] -------------
__global__ __launch_bounds__(128) void spec_stage2_coef_kern(
    const float* __restrict__ partials, const float* __restrict__ evals,
    const float* __restrict__ dt, u16* __restrict__ ys_t)
{
    int b = blockIdx.x >> 7;
    int k = blockIdx.x & 127;
    int c = threadIdx.x;
    const float* p = partials + (size_t)b * 128 * 16384 + (size_t)k * 128 + c;
    float s = 0.f;
#pragma unroll 8
    for (int pb = 0; pb < 128; pb++) s += p[(size_t)pb * 16384];
    float co = expf(-evals[b * 128 + k] * dt[c]);
    ys_t[((size_t)b * 128 + c) * 128 + k] = f2b(s * co);
}

// ------------- MFMA GEMM: out[m,0:128] = act(A[m,:KK] @ W + bias + resid), bf16 out -------------
template <int KK, bool CONCAT3, bool RELU, bool RESID, bool HASBIAS, bool AF32>
__global__ __launch_bounds__(256) void mgemm_kern(
    const void* __restrict__ A0v, const void* __restrict__ A1v, const void* __restrict__ A2v,
    const u16* __restrict__ Wp, const float* __restrict__ bias,
    const u16* __restrict__ resid, u16* __restrict__ outp,
    size_t aBatch, size_t wBatch, size_t oBatch)
{
    __shared__ u16 sA[64][72];    // padded: 144B row stride
    __shared__ u16 sB[128][72];
    int z = blockIdx.z;
    const u16* Wb = Wp + wBatch * (size_t)z;
    size_t aOff = aBatch * (size_t)z;
    size_t oOff = oBatch * (size_t)z;

    int t = threadIdx.x;
    int m0 = blockIdx.x * 64;
    int wv = t >> 6;
    int lane = t & 63;
    int quad = lane >> 4;
    int r16 = lane & 15;
    int mw = (wv & 1) * 32;
    int nw = (wv >> 1) * 64;

    f32x4 acc[2][4];
#pragma unroll
    for (int i = 0; i < 2; i++)
#pragma unroll
        for (int j = 0; j < 4; j++) acc[i][j] = (f32x4){0.f, 0.f, 0.f, 0.f};

#pragma unroll 1
    for (int kt = 0; kt < KK / 64; kt++) {
        int kbase = kt * 64;
        const void* Ap;
        if (CONCAT3) Ap = (kbase < 128) ? A0v : (kbase < 256) ? A1v : A2v;
        else Ap = A0v;
        int kloc = CONCAT3 ? (kbase & 127) : kbase;

        __syncthreads();
        if (AF32) {
            const float* Af = (const float*)Ap + aOff;
#pragma unroll
            for (int p = 0; p < 4; p++) {
                int idx = p * 256 + t;       // 0..1023
                int row = idx >> 4;          // 64 rows
                int seg = idx & 15;          // 16 segs of 4 floats
                float4 v = *(const float4*)(Af + (size_t)(m0 + row) * 128 + kloc + seg * 4);
                ushort4 h;
                h.x = f2b(v.x); h.y = f2b(v.y); h.z = f2b(v.z); h.w = f2b(v.w);
                *(ushort4*)&sA[row][seg * 4] = h;
            }
        } else {
            const u16* Ah = (const u16*)Ap + aOff;
#pragma unroll
            for (int p = 0; p < 2; p++) {
                int idx = p * 256 + t;       // 0..511
                int row = idx >> 3;          // 64 rows
                int seg = idx & 7;           // 8 segs of 8 u16
                *(uint4*)&sA[row][seg * 8] =
                    *(const uint4*)(Ah + (size_t)(m0 + row) * 128 + kloc + seg * 8);
            }
        }
        {
#pragma unroll
            for (int p = 0; p < 4; p++) {
                int idx = p * 256 + t;       // 0..1023
                int n = idx >> 3;            // 128 n
                int seg = idx & 7;           // 8 segs of 8 u16
                *(uint4*)&sB[n][seg * 8] =
                    *(const uint4*)(Wb + (size_t)n * KK + kbase + seg * 8);
            }
        }
        __syncthreads();

#pragma unroll
        for (int ks = 0; ks < 2; ks++) {
            int ko = ks * 32 + quad * 8;
            bf16x8 a0 = *(const bf16x8*)&sA[mw + r16][ko];
            bf16x8 a1 = *(const bf16x8*)&sA[mw + 16 + r16][ko];
            bf16x8 b0 = *(const bf16x8*)&sB[nw + r16][ko];
            bf16x8 b1 = *(const bf16x8*)&sB[nw + 16 + r16][ko];
            bf16x8 b2 = *(const bf16x8*)&sB[nw + 32 + r16][ko];
            bf16x8 b3 = *(const bf16x8*)&sB[nw + 48 + r16][ko];
            acc[0][0] = __builtin_amdgcn_mfma_f32_16x16x32_bf16(a0, b0, acc[0][0], 0, 0, 0);
            acc[0][1] = __builtin_amdgcn_mfma_f32_16x16x32_bf16(a0, b1, acc[0][1], 0, 0, 0);
            acc[0][2] = __builtin_amdgcn_mfma_f32_16x16x32_bf16(a0, b2, acc[0][2], 0, 0, 0);
            acc[0][3] = __builtin_amdgcn_mfma_f32_16x16x32_bf16(a0, b3, acc[0][3], 0, 0, 0);
            acc[1][0] = __builtin_amdgcn_mfma_f32_16x16x32_bf16(a1, b0, acc[1][0], 0, 0, 0);
            acc[1][1] = __builtin_amdgcn_mfma_f32_16x16x32_bf16(a1, b1, acc[1][1], 0, 0, 0);
            acc[1][2] = __builtin_amdgcn_mfma_f32_16x16x32_bf16(a1, b2, acc[1][2], 0, 0, 0);
            acc[1][3] = __builtin_amdgcn_mfma_f32_16x16x32_bf16(a1, b3, acc[1][3], 0, 0, 0);
        }
    }

    // epilogue: D[row=quad*4+reg][col=r16] per 16x16 tile
#pragma unroll
    for (int nt = 0; nt < 4; nt++) {
        int col = nw + nt * 16 + r16;
        float bv = HASBIAS ? bias[col] : 0.f;
#pragma unroll
        for (int mt = 0; mt < 2; mt++) {
#pragma unroll
            for (int reg = 0; reg < 4; reg++) {
                int row = m0 + mw + mt * 16 + quad * 4 + reg;
                float v = acc[mt][nt][reg] + bv;
                if (RESID) v += b2f(resid[(size_t)row * 128 + col]);
                if (RELU) v = fmaxf(v, 0.f);
                outp[oOff + (size_t)row * 128 + col] = f2b(v);
            }
        }
    }
}

// ------------- FUSED spMM + MFMA rotation + tanh (all batches via z) -------------
// phase 1: each wave computes 16 CSR rows of gX/gY (bf16) directly into LDS
// phase 2: Breal = [gX|gY] @ WR1, Bimag = [gY|gX] @ WR2 (K=256)
// epilogue: gf = tanh(gX*Breal + gY*Bimag), gx/gy read from LDS
__global__ __launch_bounds__(256) void spmm_rotate_kern(
    const int* __restrict__ rowptr, const int* __restrict__ scols,
    const float* __restrict__ svx, const float* __restrict__ svy,
    const u16* __restrict__ xd, const u16* __restrict__ WR1,
    const u16* __restrict__ WR2, u16* __restrict__ gf)
{
    __shared__ u16 sGX[64][136];  // 64 rows x K=128 (+8 pad)
    __shared__ u16 sGY[64][136];
    __shared__ u16 sB1[128][72];  // n x 64-k chunk
    __shared__ u16 sB2[128][72];

    const size_t NZ = (size_t)N_ * 128;
    int z = blockIdx.z;
    const float* svx_b = svx + (size_t)z * E_;
    const float* svy_b = svy + (size_t)z * E_;
    const u16* xd_b = xd + (size_t)z * NZ;
    u16* gf_b = gf + (size_t)z * NZ;

    int t = threadIdx.x;
    int m0 = blockIdx.x * 64;
    int wv = t >> 6;
    int lane = t & 63;
    int quad = lane >> 4;
    int r16 = lane & 15;
    int mw = (wv & 1) * 32;
    int nw = (wv >> 1) * 64;
    int c2 = lane * 2;

    // ---- phase 1: block-local dual spMM into LDS (wave wv: rows wv*16..wv*16+15) ----
#pragma unroll 1
    for (int rr = wv * 16; rr < wv * 16 + 16; rr++) {
        int r = m0 + rr;
        int beg = rowptr[r], end = rowptr[r + 1];
        float ax0 = 0.f, ax1 = 0.f, ay0 = 0.f, ay1 = 0.f;
        for (int j = beg; j < end; j++) {
            int col = scols[j];
            u32 xw = *(const u32*)(xd_b + (size_t)col * 128 + c2);
            float x0 = b2f((u16)(xw & 0xffffu));
            float x1 = b2f((u16)(xw >> 16));
            float vx = svx_b[j], vy = svy_b[j];
            ax0 += vx * x0; ax1 += vx * x1;
            ay0 += vy * x0; ay1 += vy * x1;
        }
        *(u32*)&sGX[rr][c2] = (u32)f2b(ax0) | ((u32)f2b(ax1) << 16);
        *(u32*)&sGY[rr][c2] = (u32)f2b(ay0) | ((u32)f2b(ay1) << 16);
    }

    f32x4 accRe[2][4], accIm[2][4];
#pragma unroll
    for (int i = 0; i < 2; i++)
#pragma unroll
        for (int j = 0; j < 4; j++) {
            accRe[i][j] = (f32x4){0.f, 0.f, 0.f, 0.f};
            accIm[i][j] = (f32x4){0.f, 0.f, 0.f, 0.f};
        }

    // ---- phase 2: rotation MFMA over 4 x 64-k chunks ----
#pragma unroll 1
    for (int c = 0; c < 4; c++) {
        __syncthreads();   // c=0: also covers phase-1 LDS writes
        // stage WR1/WR2 chunk [128][64]
#pragma unroll
        for (int p = 0; p < 4; p++) {
            int idx = p * 256 + t;       // 0..1023
            int n = idx >> 3;
            int seg = idx & 7;
            *(uint4*)&sB1[n][seg * 8] = *(const uint4*)(WR1 + (size_t)n * 256 + c * 64 + seg * 8);
            *(uint4*)&sB2[n][seg * 8] = *(const uint4*)(WR2 + (size_t)n * 256 + c * 64 + seg * 8);
        }
        __syncthreads();

        const u16 (*sRe)[136] = (c < 2) ? sGX : sGY;
        const u16 (*sIm)[136] = (c < 2) ? sGY : sGX;
        int kob = (c & 1) * 64;
#pragma unroll
        for (int ks = 0; ks < 2; ks++) {
            int ko = kob + ks * 32 + quad * 8;
            int kb = ks * 32 + quad * 8;
            bf16x8 aRe0 = *(const bf16x8*)&sRe[mw + r16][ko];
            bf16x8 aRe1 = *(const bf16x8*)&sRe[mw + 16 + r16][ko];
            bf16x8 aIm0 = *(const bf16x8*)&sIm[mw + r16][ko];
            bf16x8 aIm1 = *(const bf16x8*)&sIm[mw + 16 + r16][ko];
#pragma unroll
            for (int j = 0; j < 4; j++) {
                bf16x8 b1 = *(const bf16x8*)&sB1[nw + 16 * j + r16][kb];
                bf16x8 b2 = *(const bf16x8*)&sB2[nw + 16 * j + r16][kb];
                accRe[0][j] = __builtin_amdgcn_mfma_f32_16x16x32_bf16(aRe0, b1, accRe[0][j], 0, 0, 0);
                accRe[1][j] = __builtin_amdgcn_mfma_f32_16x16x32_bf16(aRe1, b1, accRe[1][j], 0, 0, 0);
                accIm[0][j] = __builtin_amdgcn_mfma_f32_16x16x32_bf16(aIm0, b2, accIm[0][j], 0, 0, 0);
                accIm[1][j] = __builtin_amdgcn_mfma_f32_16x16x32_bf16(aIm1, b2, accIm[1][j], 0, 0, 0);
            }
        }
    }

    // ---- epilogue: gf = tanh(gX*Breal + gY*Bimag), gx/gy from LDS ----
#pragma unroll
    for (int nt = 0; nt < 4; nt++) {
        int col = nw + nt * 16 + r16;
#pragma unroll
        for (int mt = 0; mt < 2; mt++) {
#pragma unroll
            for (int reg = 0; reg < 4; reg++) {
                int lrow = mw + mt * 16 + quad * 4 + reg;
                float gx = b2f(sGX[lrow][col]);
                float gy = b2f(sGY[lrow][col]);
                float v = tanhf(gx * accRe[mt][nt][reg] + gy * accIm[mt][nt][reg]);
                gf_b[(size_t)(m0 + lrow) * 128 + col] = f2b(v);
            }
        }
    }
}

// ------------- last linear: out[m,0:3] = x[m,:] @ w_last + b_last -------------
__global__ __launch_bounds__(256) void last_linear_kern(
    const u16* __restrict__ x, const float* __restrict__ w,
    const float* __restrict__ bias, float* __restrict__ outp, int M)
{
    __shared__ float sw[128 * 3];
    int t = threadIdx.x;
    for (int i = t; i < 384; i += 256) sw[i] = w[i];
    __syncthreads();
    int wave = t >> 6;
    int lane = t & 63;
    int row = blockIdx.x * 4 + wave;
    if (row >= M) return;
    const u16* xr = x + (size_t)row * 128;
    float p0 = 0.f, p1 = 0.f, p2 = 0.f;
#pragma unroll
    for (int h = 0; h < 2; h++) {
        int c = lane + h * 64;
        float xv = b2f(xr[c]);
        p0 += xv * sw[c * 3 + 0];
        p1 += xv * sw[c * 3 + 1];
        p2 += xv * sw[c * 3 + 2];
    }
#pragma unroll
    for (int off = 32; off > 0; off >>= 1) {
        p0 += __shfl_xor(p0, off);
        p1 += __shfl_xor(p1, off);
        p2 += __shfl_xor(p2, off);
    }
    if (lane == 0) {
        float* o = outp + (size_t)row * 3;
        o[0] = p0 + bias[0];
        o[1] = p1 + bias[1];
        o[2] = p2 + bias[2];
    }
}

extern "C" void kernel_launch(void* const* d_in, const int* in_sizes, int n_in,
                              void* d_out, int out_size, void* d_ws, size_t ws_size,
                              hipStream_t stream)
{
    const float* x_in    = (const float*)d_in[0];
    const float* mass    = (const float*)d_in[1];
    const float* evals   = (const float*)d_in[2];
    const float* evecs   = (const float*)d_in[3];
    const int*   rows    = (const int*)  d_in[4];
    const int*   cols    = (const int*)  d_in[5];
    const float* gvx     = (const float*)d_in[6];
    const float* gvy     = (const float*)d_in[7];
    const float* w_first = (const float*)d_in[8];
    const float* b_first = (const float*)d_in[9];
    const float* dtimes  = (const float*)d_in[10];
    const float* A_re    = (const float*)d_in[11];
    const float* A_im    = (const float*)d_in[12];
    const float* w0      = (const float*)d_in[13];
    const float* b0      = (const float*)d_in[14];
    const float* w1      = (const float*)d_in[15];
    const float* b1      = (const float*)d_in[16];
    const float* w2      = (const float*)d_in[17];
    const float* b2      = (const float*)d_in[18];
    const float* w_last  = (const float*)d_in[19];
    const float* b_last  = (const float*)d_in[20];
    float* outp = (float*)d_out;

    const size_t SZ = (size_t)B_ * N_ * 128;   // 20,480,000 elements
    const size_t NZ = (size_t)N_ * 128;        //  5,120,000 elements

    // workspace layout (~174 MB)
    u16* P0 = (u16*)d_ws;                      // 41 MB  (x ping-pong)
    u16* P1 = P0 + SZ;                         // 41 MB  (xd ping-pong)
    u16* GF = P1 + SZ;                         // 41 MB  (grad_feat, then h2)
    float* SC = (float*)(GF + SZ);             // 41 MB  f32: spec partials / h1 / scan scratch
    u16* ys_t = (u16*)(SC + 8388608);          // 128 KB inside SC tail
    u16* WP0 = (u16*)(SC + 2 * NZ);            // packed transposed bf16 weights
    u16* WP1 = WP0 + 4 * 49152;
    u16* WP2 = WP1 + 4 * 16384;
    u16* WR1 = WP2 + 4 * 16384;                // 4 x [128][256] rotation packs
    u16* WR2 = WR1 + 4 * 32768;
    int* rowptr = (int*)(WR2 + 4 * 32768);     // N+1 (padded to 40004)
    int* nextp  = rowptr + 40004;              // N (histogram counts, then cursors)
    int* scols  = nextp + N_;                  // E sorted cols
    float* svx  = (float*)(scols + E_);        // [B][E] sorted vals
    float* svy  = svx + (size_t)B_ * E_;

    u16* x  = P0;
    u16* xd = P1;
    const int M = B_ * N_;                     // 160000

    // --- CSR build (pattern shared across blocks & X/Y) ---
    // scan + perm scratch lives in SC: SC is untouched until spec_stage1
    int* bTot  = (int*)SC;          // NB_SCAN block totals
    int* bOff  = bTot + 512;        // NB_SCAN block offsets
    int* sperm = bTot + 1024;       // E edge permutation (transient)
    hipMemsetAsync(nextp, 0, N_ * sizeof(int), stream);
    hist_kern<<<dim3((E_ + 255) / 256), 256, 0, stream>>>(rows, nextp);
    scan1_kern<<<dim3(NB_SCAN), 256, 0, stream>>>(nextp, rowptr, bTot);
    scan2_kern<<<dim3(1), 256, 0, stream>>>(bTot, bOff, rowptr + N_);
    scan3_kern<<<dim3(NB_SCAN), 256, 0, stream>>>(rowptr, nextp, bOff);
    scatter_idx_kern<<<dim3((E_ + 255) / 256), 256, 0, stream>>>(
        rows, cols, nextp, scols, sperm);
    gather_vals_kern<<<dim3((E_ + 255) / 256), 256, 0, stream>>>(
        sperm, gvx, gvy, svx, svy);

    // --- weight packing (once per launch) ---
    pack_w_kern<<<dim3(192, 1, 4), 256, 0, stream>>>(w0, WP0, 384);
    pack_w_kern<<<dim3(64, 1, 4), 256, 0, stream>>>(w1, WP1, 128);
    pack_w_kern<<<dim3(64, 1, 4), 256, 0, stream>>>(w2, WP2, 128);
    pack_rot_kern<<<dim3(128, 1, 4), 256, 0, stream>>>(A_re, A_im, WR1, WR2);

    first_linear_kern<<<dim3(M * 16 / 256), 256, 0, stream>>>(x_in, w_first, b_first, x, M);

    for (int i = 0; i < 4; i++) {
        // --- spectral diffusion ---
        spec_stage1_mfma_kern<<<dim3(128, B_), 256, 0, stream>>>(x, mass, evecs, SC);
        spec_stage2_coef_kern<<<dim3(B_ * 128), 128, 0, stream>>>(
            SC, evals, dtimes + (size_t)i * 128, ys_t);
        mgemm_kern<128, false, false, false, false, true>
            <<<dim3(N_ / 64, 1, B_), 256, 0, stream>>>(
            evecs, nullptr, nullptr, ys_t, nullptr, nullptr, xd,
            NZ, (size_t)128 * 128, NZ);
        // --- fused sparse gradients + rotation (all batches) ---
        spmm_rotate_kern<<<dim3(N_ / 64, 1, B_), 256, 0, stream>>>(
            rowptr, scols, svx, svy, xd,
            WR1 + (size_t)i * 32768, WR2 + (size_t)i * 32768, GF);
        // --- MiniMLP + residual ---
        u16* h1 = (u16*)SC;
        mgemm_kern<384, true, true, false, true, false>
            <<<dim3(M / 64), 256, 0, stream>>>(
            x, xd, GF, WP0 + (size_t)i * 49152, b0 + (size_t)i * 128, nullptr, h1, 0, 0, 0);
        mgemm_kern<128, false, true, false, true, false>
            <<<dim3(M / 64), 256, 0, stream>>>(
            h1, nullptr, nullptr, WP1 + (size_t)i * 16384, b1 + (size_t)i * 128, nullptr, GF, 0, 0, 0);
        mgemm_kern<128, false, false, true, true, false>
            <<<dim3(M / 64), 256, 0, stream>>>(
            GF, nullptr, nullptr, WP2 + (size_t)i * 16384, b2 + (size_t)i * 128, x, xd, 0, 0, 0);
        u16* tmp = x; x = xd; xd = tmp;
    }

    last_linear_kern<<<dim3(M / 4), 256, 0, stream>>>(x, w_last, b_last, outp, M);
}

// Round 5
// 1461.728 us; speedup vs baseline: 1.4496x; 1.4496x over previous
//
#include <hip/hip_runtime.h>

#define B_ 4
#define N_ 40000
#define E_ 240000
#define NB_SCAN ((N_ + 255) / 256)   // 157 scan blocks

typedef unsigned short u16;
typedef unsigned int u32;
typedef __attribute__((ext_vector_type(8))) short bf16x8;
typedef __attribute__((ext_vector_type(4))) float f32x4;

__device__ __forceinline__ float b2f(u16 h) {
    u32 u = ((u32)h) << 16;
    return __uint_as_float(u);
}
__device__ __forceinline__ u16 f2b(float f) {
    u32 u = __float_as_uint(f);
    u32 r = (u + 0x7fffu + ((u >> 16) & 1u)) >> 16;
    return (u16)r;
}
__device__ __forceinline__ float4 f4_zero() { return make_float4(0.f, 0.f, 0.f, 0.f); }

// ---------------- first linear: x = x_in @ w_first + b_first (bf16 out, 8 c/thread) ----------------
__global__ __launch_bounds__(256) void first_linear_kern(
    const float* __restrict__ x_in, const float* __restrict__ w,
    const float* __restrict__ bias, u16* __restrict__ xout, int M)
{
    __shared__ float sw[6 * 128];
    __shared__ float sb[128];
    int t = threadIdx.x;
    for (int i = t; i < 768; i += 256) sw[i] = w[i];
    if (t < 128) sb[t] = bias[t];
    __syncthreads();
    int idx = blockIdx.x * 256 + t;   // = row*16 + cg
    int row = idx >> 4;
    int cg = (idx & 15) * 8;
    if (row >= M) return;
    const float* xr = x_in + (size_t)row * 6;
    float xv[6];
#pragma unroll
    for (int j = 0; j < 6; j++) xv[j] = xr[j];
    float acc[8];
#pragma unroll
    for (int i = 0; i < 8; i++) acc[i] = sb[cg + i];
#pragma unroll
    for (int j = 0; j < 6; j++)
#pragma unroll
        for (int i = 0; i < 8; i++) acc[i] += xv[j] * sw[j * 128 + cg + i];
    ushort4 h0, h1;
    h0.x = f2b(acc[0]); h0.y = f2b(acc[1]); h0.z = f2b(acc[2]); h0.w = f2b(acc[3]);
    h1.x = f2b(acc[4]); h1.y = f2b(acc[5]); h1.z = f2b(acc[6]); h1.w = f2b(acc[7]);
    uint4 pk;
    pk.x = (u32)h0.x | ((u32)h0.y << 16);
    pk.y = (u32)h0.z | ((u32)h0.w << 16);
    pk.z = (u32)h1.x | ((u32)h1.y << 16);
    pk.w = (u32)h1.z | ((u32)h1.w << 16);
    *(uint4*)(xout + (size_t)row * 128 + cg) = pk;
}

// ------------- weight pack: dst[n][k] = bf16(src[k][n]), per block i = blockIdx.z -------------
__global__ __launch_bounds__(256) void pack_w_kern(
    const float* __restrict__ src, u16* __restrict__ dst, int K)
{
    int i = blockIdx.z;
    src += (size_t)i * K * 128;
    dst += (size_t)i * K * 128;
    int idx = blockIdx.x * 256 + threadIdx.x;  // = n*K + k
    int n = idx / K;
    int k = idx % K;
    dst[idx] = f2b(src[(size_t)k * 128 + n]);
}

// ------------- rotation weight pack: WR1[n][k256] = [Are; -Aim]^T, WR2 = [Are; Aim]^T -------------
__global__ __launch_bounds__(256) void pack_rot_kern(
    const float* __restrict__ Are, const float* __restrict__ Aim,
    u16* __restrict__ WR1, u16* __restrict__ WR2)
{
    int i = blockIdx.z;
    const float* are = Are + (size_t)i * 16384;
    const float* aim = Aim + (size_t)i * 16384;
    int idx = blockIdx.x * 256 + threadIdx.x;  // 0..32767 = n*256 + k
    int n = idx >> 8;
    int k = idx & 255;
    float v1, v2;
    if (k < 128) { float a = are[(size_t)k * 128 + n]; v1 = a; v2 = a; }
    else         { float a = aim[(size_t)(k - 128) * 128 + n]; v1 = -a; v2 = a; }
    WR1[(size_t)i * 32768 + idx] = f2b(v1);
    WR2[(size_t)i * 32768 + idx] = f2b(v2);
}

// ------------- CSR build: histogram -> 3-phase parallel scan -> scatter idx -> gather vals -------------
__global__ __launch_bounds__(256) void hist_kern(const int* __restrict__ rows, int* count)
{
    int e = blockIdx.x * 256 + threadIdx.x;
    if (e < E_) atomicAdd(&count[rows[e]], 1);
}

// inclusive scan across a 256-thread block (4 waves, shfl-based)
__device__ __forceinline__ int block_incl_scan_256(int v, int t)
{
    __shared__ int wsum[4];
    int lane = t & 63;
    int wid = t >> 6;
    int x = v;
#pragma unroll
    for (int off = 1; off < 64; off <<= 1) {
        int y = __shfl_up(x, off);
        if (lane >= off) x += y;
    }
    if (lane == 63) wsum[wid] = x;
    __syncthreads();
    if (t == 0) {
        int s = 0;
#pragma unroll
        for (int i = 0; i < 4; i++) { int tm = wsum[i]; wsum[i] = s; s += tm; }
    }
    __syncthreads();
    return x + wsum[wid];
}

// phase 1: per-block exclusive scan of counts -> rowptr (partial), block totals
__global__ __launch_bounds__(256) void scan1_kern(
    const int* __restrict__ count, int* __restrict__ excl_out,
    int* __restrict__ blockTotals)
{
    int t = threadIdx.x;
    int g = blockIdx.x * 256 + t;
    int v = (g < N_) ? count[g] : 0;
    int incl = block_incl_scan_256(v, t);
    if (g < N_) excl_out[g] = incl - v;
    if (t == 255) blockTotals[blockIdx.x] = incl;
}

// phase 2: single-block scan of 157 block totals -> exclusive block offsets + grand total
__global__ __launch_bounds__(256) void scan2_kern(
    const int* __restrict__ blockTotals, int* __restrict__ blockOffs,
    int* __restrict__ totalOut)
{
    int t = threadIdx.x;
    int v = (t < NB_SCAN) ? blockTotals[t] : 0;
    int incl = block_incl_scan_256(v, t);
    if (t < NB_SCAN) blockOffs[t] = incl - v;
    if (t == 255) *totalOut = incl;   // = E_, written to rowptr[N_]
}

// phase 3: add block offsets; materialize rowptr + nextp cursors
__global__ __launch_bounds__(256) void scan3_kern(
    int* __restrict__ rowptr, int* __restrict__ nextp,
    const int* __restrict__ blockOffs)
{
    int t = threadIdx.x;
    int g = blockIdx.x * 256 + t;
    if (g >= N_) return;
    int v = rowptr[g] + blockOffs[blockIdx.x];
    rowptr[g] = v;
    nextp[g] = v;
}

// scatter only indices (2 scattered u32 writes per edge)
__global__ __launch_bounds__(256) void scatter_idx_kern(
    const int* __restrict__ rows, const int* __restrict__ cols,
    int* nextp, int* __restrict__ scols, int* __restrict__ sperm)
{
    int e = blockIdx.x * 256 + threadIdx.x;
    if (e >= E_) return;
    int r = rows[e];
    int pos = atomicAdd(&nextp[r], 1);
    scols[pos] = cols[e];
    sperm[pos] = e;
}

// gather values: coalesced writes, L2-cached random reads
__global__ __launch_bounds__(256) void gather_vals_kern(
    const int* __restrict__ sperm,
    const float* __restrict__ gvx, const float* __restrict__ gvy,
    float* __restrict__ svx, float* __restrict__ svy)
{
    int pos = blockIdx.x * 256 + threadIdx.x;
    if (pos >= E_) return;
    int e = sperm[pos];
#pragma unroll
    for (int b = 0; b < B_; b++) {
        svx[(size_t)b * E_ + pos] = gvx[(size_t)b * E_ + e];
        svy[(size_t)b * E_ + pos] = gvy[(size_t)b * E_ + e];
    }
}

// ------------- CSR dual spMM (single batch), bf16 packed out, edge-unrolled x2 -------------
// 4 rows/block; each row: 64 lanes x 2 channels. gX/gY[r][c] = sum_j val[j]*xd[scols[j]][c]
__global__ __launch_bounds__(256) void spmm_csr_kern(
    const int* __restrict__ rowptr, const int* __restrict__ scols,
    const float* __restrict__ svx, const float* __restrict__ svy,
    const u16* __restrict__ xd_b, u16* __restrict__ gXh, u16* __restrict__ gYh)
{
    int t = threadIdx.x;
    int r = blockIdx.x * 4 + (t >> 6);
    int c2 = (t & 63) * 2;
    int beg = rowptr[r], end = rowptr[r + 1];
    float ax0 = 0.f, ax1 = 0.f, ay0 = 0.f, ay1 = 0.f;
    int j = beg;
    for (; j + 1 < end; j += 2) {
        int ca = scols[j], cb = scols[j + 1];
        u32 xwa = *(const u32*)(xd_b + (size_t)ca * 128 + c2);
        u32 xwb = *(const u32*)(xd_b + (size_t)cb * 128 + c2);
        float vxa = svx[j], vya = svy[j];
        float vxb = svx[j + 1], vyb = svy[j + 1];
        float xa0 = b2f((u16)(xwa & 0xffffu)), xa1 = b2f((u16)(xwa >> 16));
        float xb0 = b2f((u16)(xwb & 0xffffu)), xb1 = b2f((u16)(xwb >> 16));
        ax0 += vxa * xa0; ax1 += vxa * xa1;
        ay0 += vya * xa0; ay1 += vya * xa1;
        ax0 += vxb * xb0; ax1 += vxb * xb1;
        ay0 += vyb * xb0; ay1 += vyb * xb1;
    }
    if (j < end) {
        int col = scols[j];
        u32 xw = *(const u32*)(xd_b + (size_t)col * 128 + c2);
        float x0 = b2f((u16)(xw & 0xffffu));
        float x1 = b2f((u16)(xw >> 16));
        float vx = svx[j], vy = svy[j];
        ax0 += vx * x0; ax1 += vx * x1;
        ay0 += vy * x0; ay1 += vy * x1;
    }
    u32 px = (u32)f2b(ax0) | ((u32)f2b(ax1) << 16);
    u32 py = (u32)f2b(ay0) | ((u32)f2b(ay1) << 16);
    *(u32*)(gXh + (size_t)r * 128 + c2) = px;
    *(u32*)(gYh + (size_t)r * 128 + c2) = py;
}

// ------------- spectral projection stage 1: MFMA over transposed LDS tiles -------------
__global__ __launch_bounds__(256) void spec_stage1_mfma_kern(
    const u16* __restrict__ x, const float* __restrict__ mass,
    const float* __restrict__ evecs, float* __restrict__ partials)
{
    __shared__ __align__(16) u16 sEVh[128][40];
    __shared__ __align__(16) u16 sEVl[128][40];
    __shared__ __align__(16) u16 sXM[128][40];
    int b = blockIdx.y;
    int pb = blockIdx.x;
    const u16* xb = x + (size_t)b * N_ * 128;
    const float* mb = mass + (size_t)b * N_;
    const float* eb = evecs + (size_t)b * N_ * 128;
    float* dst = partials + ((size_t)b * 128 + pb) * 16384;

    int t = threadIdx.x;
    int wv = t >> 6;
    int lane = t & 63;
    int quad = lane >> 4;
    int r16 = lane & 15;
    int kb = wv * 32;
    int kc = (t & 63) * 2;
    int nh = wv;

    f32x4 acc[2][8];
#pragma unroll
    for (int i = 0; i < 2; i++)
#pragma unroll
        for (int j = 0; j < 8; j++) acc[i][j] = (f32x4){0.f, 0.f, 0.f, 0.f};

    for (int ch = pb; ch < N_ / 32; ch += 128) {
        int nbase = ch * 32 + nh * 8;
        float4 m0 = *(const float4*)(mb + nbase);
        float4 m1 = *(const float4*)(mb + nbase + 4);
        float mm[8] = {m0.x, m0.y, m0.z, m0.w, m1.x, m1.y, m1.z, m1.w};
        u32 eh0[4], eh1[4], el0[4], el1[4], xq0[4], xq1[4];
#pragma unroll
        for (int jp = 0; jp < 4; jp++) {
            eh0[jp] = 0; eh1[jp] = 0; el0[jp] = 0;
            el1[jp] = 0; xq0[jp] = 0; xq1[jp] = 0;
        }
#pragma unroll
        for (int j = 0; j < 8; j++) {
            float2 e = *(const float2*)(eb + (size_t)(nbase + j) * 128 + kc);
            u32 xw = *(const u32*)(xb + (size_t)(nbase + j) * 128 + kc);
            u16 h0 = f2b(e.x);
            u16 h1 = f2b(e.y);
            u16 l0 = f2b(e.x - b2f(h0));
            u16 l1 = f2b(e.y - b2f(h1));
            u16 q0 = f2b(b2f((u16)(xw & 0xffffu)) * mm[j]);
            u16 q1 = f2b(b2f((u16)(xw >> 16)) * mm[j]);
            int sh = (j & 1) * 16;
            int jp = j >> 1;
            eh0[jp] |= ((u32)h0) << sh; eh1[jp] |= ((u32)h1) << sh;
            el0[jp] |= ((u32)l0) << sh; el1[jp] |= ((u32)l1) << sh;
            xq0[jp] |= ((u32)q0) << sh; xq1[jp] |= ((u32)q1) << sh;
        }
        __syncthreads();
        *(uint4*)&sEVh[kc][nh * 8]     = make_uint4(eh0[0], eh0[1], eh0[2], eh0[3]);
        *(uint4*)&sEVh[kc + 1][nh * 8] = make_uint4(eh1[0], eh1[1], eh1[2], eh1[3]);
        *(uint4*)&sEVl[kc][nh * 8]     = make_uint4(el0[0], el0[1], el0[2], el0[3]);
        *(uint4*)&sEVl[kc + 1][nh * 8] = make_uint4(el1[0], el1[1], el1[2], el1[3]);
        *(uint4*)&sXM[kc][nh * 8]      = make_uint4(xq0[0], xq0[1], xq0[2], xq0[3]);
        *(uint4*)&sXM[kc + 1][nh * 8]  = make_uint4(xq1[0], xq1[1], xq1[2], xq1[3]);
        __syncthreads();

        bf16x8 ah0 = *(const bf16x8*)&sEVh[kb + r16][quad * 8];
        bf16x8 ah1 = *(const bf16x8*)&sEVh[kb + 16 + r16][quad * 8];
        bf16x8 al0 = *(const bf16x8*)&sEVl[kb + r16][quad * 8];
        bf16x8 al1 = *(const bf16x8*)&sEVl[kb + 16 + r16][quad * 8];
#pragma unroll
        for (int nt = 0; nt < 8; nt++) {
            bf16x8 bx = *(const bf16x8*)&sXM[nt * 16 + r16][quad * 8];
            acc[0][nt] = __builtin_amdgcn_mfma_f32_16x16x32_bf16(ah0, bx, acc[0][nt], 0, 0, 0);
            acc[1][nt] = __builtin_amdgcn_mfma_f32_16x16x32_bf16(ah1, bx, acc[1][nt], 0, 0, 0);
            acc[0][nt] = __builtin_amdgcn_mfma_f32_16x16x32_bf16(al0, bx, acc[0][nt], 0, 0, 0);
            acc[1][nt] = __builtin_amdgcn_mfma_f32_16x16x32_bf16(al1, bx, acc[1][nt], 0, 0, 0);
        }
    }

#pragma unroll
    for (int mt = 0; mt < 2; mt++)
#pragma unroll
        for (int nt = 0; nt < 8; nt++)
#pragma unroll
            for (int reg = 0; reg < 4; reg++) {
                int kk = kb + mt * 16 + quad * 4 + reg;
                int cc = nt * 16 + r16;
                dst[(size_t)kk * 128 + cc] = acc[mt][nt][reg];
            }
}

// ------------- stage 2 + coefficients, TRANSPOSED bf16 out: ys_t[b][c][k] -------------
__global__ __launch_bounds__(128) void spec_stage2_coef_kern(
    const float* __restrict__ partials, const float* __restrict__ evals,
    const float* __restrict__ dt, u16* __restrict__ ys_t)
{
    int b = blockIdx.x >> 7;
    int k = blockIdx.x & 127;
    int c = threadIdx.x;
    const float* p = partials + (size_t)b * 128 * 16384 + (size_t)k * 128 + c;
    float s = 0.f;
#pragma unroll 8
    for (int pb = 0; pb < 128; pb++) s += p[(size_t)pb * 16384];
    float co = expf(-evals[b * 128 + k] * dt[c]);
    ys_t[((size_t)b * 128 + c) * 128 + k] = f2b(s * co);
}

// ------------- MFMA GEMM: out[m,0:128] = A[m,:KK] @ W (bf16 out); AF32 path for evecs ------
template <int KK, bool AF32>
__global__ __launch_bounds__(256) void mgemm_kern(
    const void* __restrict__ A0v,
    const u16* __restrict__ Wp, u16* __restrict__ outp,
    size_t aBatch, size_t wBatch, size_t oBatch)
{
    __shared__ u16 sA[64][72];
    __shared__ u16 sB[128][72];
    int z = blockIdx.z;
    const u16* Wb = Wp + wBatch * (size_t)z;
    size_t aOff = aBatch * (size_t)z;
    size_t oOff = oBatch * (size_t)z;

    int t = threadIdx.x;
    int m0 = blockIdx.x * 64;
    int wv = t >> 6;
    int lane = t & 63;
    int quad = lane >> 4;
    int r16 = lane & 15;
    int mw = (wv & 1) * 32;
    int nw = (wv >> 1) * 64;

    f32x4 acc[2][4];
#pragma unroll
    for (int i = 0; i < 2; i++)
#pragma unroll
        for (int j = 0; j < 4; j++) acc[i][j] = (f32x4){0.f, 0.f, 0.f, 0.f};

#pragma unroll 1
    for (int kt = 0; kt < KK / 64; kt++) {
        int kbase = kt * 64;
        __syncthreads();
        if (AF32) {
            const float* Af = (const float*)A0v + aOff;
#pragma unroll
            for (int p = 0; p < 4; p++) {
                int idx = p * 256 + t;
                int row = idx >> 4;
                int seg = idx & 15;
                float4 v = *(const float4*)(Af + (size_t)(m0 + row) * 128 + kbase + seg * 4);
                ushort4 h;
                h.x = f2b(v.x); h.y = f2b(v.y); h.z = f2b(v.z); h.w = f2b(v.w);
                *(ushort4*)&sA[row][seg * 4] = h;
            }
        } else {
            const u16* Ah = (const u16*)A0v + aOff;
#pragma unroll
            for (int p = 0; p < 2; p++) {
                int idx = p * 256 + t;
                int row = idx >> 3;
                int seg = idx & 7;
                *(uint4*)&sA[row][seg * 8] =
                    *(const uint4*)(Ah + (size_t)(m0 + row) * 128 + kbase + seg * 8);
            }
        }
        {
#pragma unroll
            for (int p = 0; p < 4; p++) {
                int idx = p * 256 + t;
                int n = idx >> 3;
                int seg = idx & 7;
                *(uint4*)&sB[n][seg * 8] =
                    *(const uint4*)(Wb + (size_t)n * KK + kbase + seg * 8);
            }
        }
        __syncthreads();

#pragma unroll
        for (int ks = 0; ks < 2; ks++) {
            int ko = ks * 32 + quad * 8;
            bf16x8 a0 = *(const bf16x8*)&sA[mw + r16][ko];
            bf16x8 a1 = *(const bf16x8*)&sA[mw + 16 + r16][ko];
            bf16x8 b0 = *(const bf16x8*)&sB[nw + r16][ko];
            bf16x8 b1 = *(const bf16x8*)&sB[nw + 16 + r16][ko];
            bf16x8 b2 = *(const bf16x8*)&sB[nw + 32 + r16][ko];
            bf16x8 b3 = *(const bf16x8*)&sB[nw + 48 + r16][ko];
            acc[0][0] = __builtin_amdgcn_mfma_f32_16x16x32_bf16(a0, b0, acc[0][0], 0, 0, 0);
            acc[0][1] = __builtin_amdgcn_mfma_f32_16x16x32_bf16(a0, b1, acc[0][1], 0, 0, 0);
            acc[0][2] = __builtin_amdgcn_mfma_f32_16x16x32_bf16(a0, b2, acc[0][2], 0, 0, 0);
            acc[0][3] = __builtin_amdgcn_mfma_f32_16x16x32_bf16(a0, b3, acc[0][3], 0, 0, 0);
            acc[1][0] = __builtin_amdgcn_mfma_f32_16x16x32_bf16(a1, b0, acc[1][0], 0, 0, 0);
            acc[1][1] = __builtin_amdgcn_mfma_f32_16x16x32_bf16(a1, b1, acc[1][1], 0, 0, 0);
            acc[1][2] = __builtin_amdgcn_mfma_f32_16x16x32_bf16(a1, b2, acc[1][2], 0, 0, 0);
            acc[1][3] = __builtin_amdgcn_mfma_f32_16x16x32_bf16(a1, b3, acc[1][3], 0, 0, 0);
        }
    }

#pragma unroll
    for (int nt = 0; nt < 4; nt++) {
        int col = nw + nt * 16 + r16;
#pragma unroll
        for (int mt = 0; mt < 2; mt++) {
#pragma unroll
            for (int reg = 0; reg < 4; reg++) {
                int row = m0 + mw + mt * 16 + quad * 4 + reg;
                outp[oOff + (size_t)row * 128 + col] = f2b(acc[mt][nt][reg]);
            }
        }
    }
}

// ------------- MFMA rotation + tanh (single batch, bf16 gX/gY inputs) -------------
__global__ __launch_bounds__(256) void rotate_mfma_kern(
    const u16* __restrict__ gXh, const u16* __restrict__ gYh,
    const u16* __restrict__ WR1, const u16* __restrict__ WR2,
    u16* __restrict__ gf_b)
{
    __shared__ u16 sGX[64][136];
    __shared__ u16 sGY[64][136];
    __shared__ u16 sB1[128][72];
    __shared__ u16 sB2[128][72];

    int t = threadIdx.x;
    int m0 = blockIdx.x * 64;
    int wv = t >> 6;
    int lane = t & 63;
    int quad = lane >> 4;
    int r16 = lane & 15;
    int mw = (wv & 1) * 32;
    int nw = (wv >> 1) * 64;

#pragma unroll
    for (int p = 0; p < 4; p++) {
        int idx = p * 256 + t;
        int row = idx >> 4;
        int seg = idx & 15;
        *(uint4*)&sGX[row][seg * 8] = *(const uint4*)(gXh + (size_t)(m0 + row) * 128 + seg * 8);
        *(uint4*)&sGY[row][seg * 8] = *(const uint4*)(gYh + (size_t)(m0 + row) * 128 + seg * 8);
    }

    f32x4 accRe[2][4], accIm[2][4];
#pragma unroll
    for (int i = 0; i < 2; i++)
#pragma unroll
        for (int j = 0; j < 4; j++) {
            accRe[i][j] = (f32x4){0.f, 0.f, 0.f, 0.f};
            accIm[i][j] = (f32x4){0.f, 0.f, 0.f, 0.f};
        }

#pragma unroll 1
    for (int c = 0; c < 4; c++) {
        __syncthreads();
#pragma unroll
        for (int p = 0; p < 4; p++) {
            int idx = p * 256 + t;
            int n = idx >> 3;
            int seg = idx & 7;
            *(uint4*)&sB1[n][seg * 8] = *(const uint4*)(WR1 + (size_t)n * 256 + c * 64 + seg * 8);
            *(uint4*)&sB2[n][seg * 8] = *(const uint4*)(WR2 + (size_t)n * 256 + c * 64 + seg * 8);
        }
        __syncthreads();

        const u16 (*sRe)[136] = (c < 2) ? sGX : sGY;
        const u16 (*sIm)[136] = (c < 2) ? sGY : sGX;
        int kob = (c & 1) * 64;
#pragma unroll
        for (int ks = 0; ks < 2; ks++) {
            int ko = kob + ks * 32 + quad * 8;
            int kb = ks * 32 + quad * 8;
            bf16x8 aRe0 = *(const bf16x8*)&sRe[mw + r16][ko];
            bf16x8 aRe1 = *(const bf16x8*)&sRe[mw + 16 + r16][ko];
            bf16x8 aIm0 = *(const bf16x8*)&sIm[mw + r16][ko];
            bf16x8 aIm1 = *(const bf16x8*)&sIm[mw + 16 + r16][ko];
#pragma unroll
            for (int j = 0; j < 4; j++) {
                bf16x8 b1 = *(const bf16x8*)&sB1[nw + 16 * j + r16][kb];
                bf16x8 b2 = *(const bf16x8*)&sB2[nw + 16 * j + r16][kb];
                accRe[0][j] = __builtin_amdgcn_mfma_f32_16x16x32_bf16(aRe0, b1, accRe[0][j], 0, 0, 0);
                accRe[1][j] = __builtin_amdgcn_mfma_f32_16x16x32_bf16(aRe1, b1, accRe[1][j], 0, 0, 0);
                accIm[0][j] = __builtin_amdgcn_mfma_f32_16x16x32_bf16(aIm0, b2, accIm[0][j], 0, 0, 0);
                accIm[1][j] = __builtin_amdgcn_mfma_f32_16x16x32_bf16(aIm1, b2, accIm[1][j], 0, 0, 0);
            }
        }
    }

#pragma unroll
    for (int nt = 0; nt < 4; nt++) {
        int col = nw + nt * 16 + r16;
#pragma unroll
        for (int mt = 0; mt < 2; mt++) {
#pragma unroll
            for (int reg = 0; reg < 4; reg++) {
                int row = m0 + mw + mt * 16 + quad * 4 + reg;
                float gx = b2f(gXh[(size_t)row * 128 + col]);
                float gy = b2f(gYh[(size_t)row * 128 + col]);
                float v = tanhf(gx * accRe[mt][nt][reg] + gy * accIm[mt][nt][reg]);
                gf_b[(size_t)row * 128 + col] = f2b(v);
            }
        }
    }
}

// ------------- FUSED 3-layer MiniMLP: out = h2@W2 + b2 + x, h_i kept in LDS -------------
// h1 = relu(concat(x,xd,gf)@W0 + b0); h2 = relu(h1@W1 + b1); out = h2@W2 + b2 + resid
__global__ __launch_bounds__(256) void mlp_fused_kern(
    const u16* __restrict__ xA, const u16* __restrict__ xdA, const u16* __restrict__ gfA,
    const u16* __restrict__ W0, const u16* __restrict__ W1, const u16* __restrict__ W2,
    const float* __restrict__ b0, const float* __restrict__ b1, const float* __restrict__ b2,
    const u16* __restrict__ resid, u16* __restrict__ outp)
{
    __shared__ u16 sA[64][72];
    __shared__ u16 sB[128][72];
    __shared__ u16 sH[64][136];   // h1 then h2 (barrier-separated reuse)

    int t = threadIdx.x;
    int m0 = blockIdx.x * 64;
    int wv = t >> 6;
    int lane = t & 63;
    int quad = lane >> 4;
    int r16 = lane & 15;
    int mw = (wv & 1) * 32;
    int nw = (wv >> 1) * 64;

    f32x4 acc[2][4];
#pragma unroll
    for (int i = 0; i < 2; i++)
#pragma unroll
        for (int j = 0; j < 4; j++) acc[i][j] = (f32x4){0.f, 0.f, 0.f, 0.f};

    // ---- stage 0: K=384 over concat(x, xd, gf) ----
#pragma unroll 1
    for (int kt = 0; kt < 6; kt++) {
        int kbase = kt * 64;
        const u16* Ap = (kbase < 128) ? xA : (kbase < 256) ? xdA : gfA;
        int kloc = kbase & 127;
        __syncthreads();
#pragma unroll
        for (int p = 0; p < 2; p++) {
            int idx = p * 256 + t;
            int row = idx >> 3;
            int seg = idx & 7;
            *(uint4*)&sA[row][seg * 8] =
                *(const uint4*)(Ap + (size_t)(m0 + row) * 128 + kloc + seg * 8);
        }
#pragma unroll
        for (int p = 0; p < 4; p++) {
            int idx = p * 256 + t;
            int n = idx >> 3;
            int seg = idx & 7;
            *(uint4*)&sB[n][seg * 8] = *(const uint4*)(W0 + (size_t)n * 384 + kbase + seg * 8);
        }
        __syncthreads();
#pragma unroll
        for (int ks = 0; ks < 2; ks++) {
            int ko = ks * 32 + quad * 8;
            bf16x8 a0 = *(const bf16x8*)&sA[mw + r16][ko];
            bf16x8 a1 = *(const bf16x8*)&sA[mw + 16 + r16][ko];
#pragma unroll
            for (int j = 0; j < 4; j++) {
                bf16x8 bj = *(const bf16x8*)&sB[nw + 16 * j + r16][ko];
                acc[0][j] = __builtin_amdgcn_mfma_f32_16x16x32_bf16(a0, bj, acc[0][j], 0, 0, 0);
                acc[1][j] = __builtin_amdgcn_mfma_f32_16x16x32_bf16(a1, bj, acc[1][j], 0, 0, 0);
            }
        }
    }
    // h1 -> sH (bias + relu + bf16)
#pragma unroll
    for (int nt = 0; nt < 4; nt++) {
        int col = nw + nt * 16 + r16;
        float bv = b0[col];
#pragma unroll
        for (int mt = 0; mt < 2; mt++)
#pragma unroll
            for (int reg = 0; reg < 4; reg++) {
                int rl = mw + mt * 16 + quad * 4 + reg;
                sH[rl][col] = f2b(fmaxf(acc[mt][nt][reg] + bv, 0.f));
            }
    }

    // ---- stage 1: h2 = relu(h1 @ W1 + b1), K=128, A from sH ----
#pragma unroll
    for (int i = 0; i < 2; i++)
#pragma unroll
        for (int j = 0; j < 4; j++) acc[i][j] = (f32x4){0.f, 0.f, 0.f, 0.f};
#pragma unroll 1
    for (int kt = 0; kt < 2; kt++) {
        int kbase = kt * 64;
        __syncthreads();   // kt=0: covers sH(h1) writes; also previous chunk's sB reads
#pragma unroll
        for (int p = 0; p < 4; p++) {
            int idx = p * 256 + t;
            int n = idx >> 3;
            int seg = idx & 7;
            *(uint4*)&sB[n][seg * 8] = *(const uint4*)(W1 + (size_t)n * 128 + kbase + seg * 8);
        }
        __syncthreads();
#pragma unroll
        for (int ks = 0; ks < 2; ks++) {
            int ko = kbase + ks * 32 + quad * 8;
            int kb = ks * 32 + quad * 8;
            bf16x8 a0 = *(const bf16x8*)&sH[mw + r16][ko];
            bf16x8 a1 = *(const bf16x8*)&sH[mw + 16 + r16][ko];
#pragma unroll
            for (int j = 0; j < 4; j++) {
                bf16x8 bj = *(const bf16x8*)&sB[nw + 16 * j + r16][kb];
                acc[0][j] = __builtin_amdgcn_mfma_f32_16x16x32_bf16(a0, bj, acc[0][j], 0, 0, 0);
                acc[1][j] = __builtin_amdgcn_mfma_f32_16x16x32_bf16(a1, bj, acc[1][j], 0, 0, 0);
            }
        }
    }
    __syncthreads();   // all waves done reading h1
#pragma unroll
    for (int nt = 0; nt < 4; nt++) {
        int col = nw + nt * 16 + r16;
        float bv = b1[col];
#pragma unroll
        for (int mt = 0; mt < 2; mt++)
#pragma unroll
            for (int reg = 0; reg < 4; reg++) {
                int rl = mw + mt * 16 + quad * 4 + reg;
                sH[rl][col] = f2b(fmaxf(acc[mt][nt][reg] + bv, 0.f));
            }
    }

    // ---- stage 2: out = h2 @ W2 + b2 + resid ----
#pragma unroll
    for (int i = 0; i < 2; i++)
#pragma unroll
        for (int j = 0; j < 4; j++) acc[i][j] = (f32x4){0.f, 0.f, 0.f, 0.f};
#pragma unroll 1
    for (int kt = 0; kt < 2; kt++) {
        int kbase = kt * 64;
        __syncthreads();   // kt=0: covers sH(h2) writes
#pragma unroll
        for (int p = 0; p < 4; p++) {
            int idx = p * 256 + t;
            int n = idx >> 3;
            int seg = idx & 7;
            *(uint4*)&sB[n][seg * 8] = *(const uint4*)(W2 + (size_t)n * 128 + kbase + seg * 8);
        }
        __syncthreads();
#pragma unroll
        for (int ks = 0; ks < 2; ks++) {
            int ko = kbase + ks * 32 + quad * 8;
            int kb = ks * 32 + quad * 8;
            bf16x8 a0 = *(const bf16x8*)&sH[mw + r16][ko];
            bf16x8 a1 = *(const bf16x8*)&sH[mw + 16 + r16][ko];
#pragma unroll
            for (int j = 0; j < 4; j++) {
                bf16x8 bj = *(const bf16x8*)&sB[nw + 16 * j + r16][kb];
                acc[0][j] = __builtin_amdgcn_mfma_f32_16x16x32_bf16(a0, bj, acc[0][j], 0, 0, 0);
                acc[1][j] = __builtin_amdgcn_mfma_f32_16x16x32_bf16(a1, bj, acc[1][j], 0, 0, 0);
            }
        }
    }
#pragma unroll
    for (int nt = 0; nt < 4; nt++) {
        int col = nw + nt * 16 + r16;
        float bv = b2[col];
#pragma unroll
        for (int mt = 0; mt < 2; mt++)
#pragma unroll
            for (int reg = 0; reg < 4; reg++) {
                int row = m0 + mw + mt * 16 + quad * 4 + reg;
                float v = acc[mt][nt][reg] + bv + b2f(resid[(size_t)row * 128 + col]);
                outp[(size_t)row * 128 + col] = f2b(v);
            }
    }
}

// ------------- last linear: out[m,0:3] = x[m,:] @ w_last + b_last -------------
__global__ __launch_bounds__(256) void last_linear_kern(
    const u16* __restrict__ x, const float* __restrict__ w,
    const float* __restrict__ bias, float* __restrict__ outp, int M)
{
    __shared__ float sw[128 * 3];
    int t = threadIdx.x;
    for (int i = t; i < 384; i += 256) sw[i] = w[i];
    __syncthreads();
    int wave = t >> 6;
    int lane = t & 63;
    int row = blockIdx.x * 4 + wave;
    if (row >= M) return;
    const u16* xr = x + (size_t)row * 128;
    float p0 = 0.f, p1 = 0.f, p2 = 0.f;
#pragma unroll
    for (int h = 0; h < 2; h++) {
        int c = lane + h * 64;
        float xv = b2f(xr[c]);
        p0 += xv * sw[c * 3 + 0];
        p1 += xv * sw[c * 3 + 1];
        p2 += xv * sw[c * 3 + 2];
    }
#pragma unroll
    for (int off = 32; off > 0; off >>= 1) {
        p0 += __shfl_xor(p0, off);
        p1 += __shfl_xor(p1, off);
        p2 += __shfl_xor(p2, off);
    }
    if (lane == 0) {
        float* o = outp + (size_t)row * 3;
        o[0] = p0 + bias[0];
        o[1] = p1 + bias[1];
        o[2] = p2 + bias[2];
    }
}

extern "C" void kernel_launch(void* const* d_in, const int* in_sizes, int n_in,
                              void* d_out, int out_size, void* d_ws, size_t ws_size,
                              hipStream_t stream)
{
    const float* x_in    = (const float*)d_in[0];
    const float* mass    = (const float*)d_in[1];
    const float* evals   = (const float*)d_in[2];
    const float* evecs   = (const float*)d_in[3];
    const int*   rows    = (const int*)  d_in[4];
    const int*   cols    = (const int*)  d_in[5];
    const float* gvx     = (const float*)d_in[6];
    const float* gvy     = (const float*)d_in[7];
    const float* w_first = (const float*)d_in[8];
    const float* b_first = (const float*)d_in[9];
    const float* dtimes  = (const float*)d_in[10];
    const float* A_re    = (const float*)d_in[11];
    const float* A_im    = (const float*)d_in[12];
    const float* w0      = (const float*)d_in[13];
    const float* b0      = (const float*)d_in[14];
    const float* w1      = (const float*)d_in[15];
    const float* b1      = (const float*)d_in[16];
    const float* w2      = (const float*)d_in[17];
    const float* b2      = (const float*)d_in[18];
    const float* w_last  = (const float*)d_in[19];
    const float* b_last  = (const float*)d_in[20];
    float* outp = (float*)d_out;

    const size_t SZ = (size_t)B_ * N_ * 128;   // 20,480,000 elements
    const size_t NZ = (size_t)N_ * 128;        //  5,120,000 elements

    // workspace layout (~174 MB)
    u16* P0 = (u16*)d_ws;                      // 41 MB  (x ping-pong)
    u16* P1 = P0 + SZ;                         // 41 MB  (xd ping-pong)
    u16* GF = P1 + SZ;                         // 41 MB  (grad_feat)
    float* SC = (float*)(GF + SZ);             // 41 MB  f32: spec partials / gXh,gYh / scan scratch
    u16* ys_t = (u16*)(SC + 8388608);          // 128 KB inside SC tail
    u16* WP0 = (u16*)(SC + 2 * NZ);            // packed transposed bf16 weights
    u16* WP1 = WP0 + 4 * 49152;
    u16* WP2 = WP1 + 4 * 16384;
    u16* WR1 = WP2 + 4 * 16384;                // 4 x [128][256] rotation packs
    u16* WR2 = WR1 + 4 * 32768;
    int* rowptr = (int*)(WR2 + 4 * 32768);     // N+1 (padded to 40004)
    int* nextp  = rowptr + 40004;              // N (histogram counts, then cursors)
    int* scols  = nextp + N_;                  // E sorted cols
    float* svx  = (float*)(scols + E_);        // [B][E] sorted vals
    float* svy  = svx + (size_t)B_ * E_;

    u16* x  = P0;
    u16* xd = P1;
    const int M = B_ * N_;                     // 160000

    // --- CSR build (pattern shared across blocks & X/Y) ---
    int* bTot  = (int*)SC;          // NB_SCAN block totals
    int* bOff  = bTot + 512;        // NB_SCAN block offsets
    int* sperm = bTot + 1024;       // E edge permutation (transient)
    hipMemsetAsync(nextp, 0, N_ * sizeof(int), stream);
    hist_kern<<<dim3((E_ + 255) / 256), 256, 0, stream>>>(rows, nextp);
    scan1_kern<<<dim3(NB_SCAN), 256, 0, stream>>>(nextp, rowptr, bTot);
    scan2_kern<<<dim3(1), 256, 0, stream>>>(bTot, bOff, rowptr + N_);
    scan3_kern<<<dim3(NB_SCAN), 256, 0, stream>>>(rowptr, nextp, bOff);
    scatter_idx_kern<<<dim3((E_ + 255) / 256), 256, 0, stream>>>(
        rows, cols, nextp, scols, sperm);
    gather_vals_kern<<<dim3((E_ + 255) / 256), 256, 0, stream>>>(
        sperm, gvx, gvy, svx, svy);

    // --- weight packing (once per launch) ---
    pack_w_kern<<<dim3(192, 1, 4), 256, 0, stream>>>(w0, WP0, 384);
    pack_w_kern<<<dim3(64, 1, 4), 256, 0, stream>>>(w1, WP1, 128);
    pack_w_kern<<<dim3(64, 1, 4), 256, 0, stream>>>(w2, WP2, 128);
    pack_rot_kern<<<dim3(128, 1, 4), 256, 0, stream>>>(A_re, A_im, WR1, WR2);

    first_linear_kern<<<dim3(M * 16 / 256), 256, 0, stream>>>(x_in, w_first, b_first, x, M);

    // bf16 gX/gY scratch inside SC (overwrites consumed partials)
    u16* gXh = (u16*)SC;
    u16* gYh = gXh + NZ;

    for (int i = 0; i < 4; i++) {
        // --- spectral diffusion ---
        spec_stage1_mfma_kern<<<dim3(128, B_), 256, 0, stream>>>(x, mass, evecs, SC);
        spec_stage2_coef_kern<<<dim3(B_ * 128), 128, 0, stream>>>(
            SC, evals, dtimes + (size_t)i * 128, ys_t);
        mgemm_kern<128, true><<<dim3(N_ / 64, 1, B_), 256, 0, stream>>>(
            evecs, ys_t, xd, NZ, (size_t)128 * 128, NZ);
        // --- sparse gradients (CSR, no atomics) + MFMA rotation, per batch ---
        for (int b = 0; b < B_; b++) {
            spmm_csr_kern<<<dim3(N_ / 4), 256, 0, stream>>>(
                rowptr, scols, svx + (size_t)b * E_, svy + (size_t)b * E_,
                xd + (size_t)b * NZ, gXh, gYh);
            rotate_mfma_kern<<<dim3(N_ / 64), 256, 0, stream>>>(
                gXh, gYh, WR1 + (size_t)i * 32768, WR2 + (size_t)i * 32768,
                GF + (size_t)b * NZ);
        }
        // --- fused MiniMLP + residual (h1/h2 stay in LDS) ---
        mlp_fused_kern<<<dim3(M / 64), 256, 0, stream>>>(
            x, xd, GF,
            WP0 + (size_t)i * 49152, WP1 + (size_t)i * 16384, WP2 + (size_t)i * 16384,
            b0 + (size_t)i * 128, b1 + (size_t)i * 128, b2 + (size_t)i * 128,
            x, xd);
        u16* tmp = x; x = xd; xd = tmp;
    }

    last_linear_kern<<<dim3(M / 4), 256, 0, stream>>>(x, w_last, b_last, outp, M);
}

// Round 6
// 1365.582 us; speedup vs baseline: 1.5516x; 1.0704x over previous
//
#include <hip/hip_runtime.h>

#define B_ 4
#define N_ 40000
#define E_ 240000
#define NB_SCAN ((N_ + 255) / 256)   // 157 scan blocks

typedef unsigned short u16;
typedef unsigned int u32;
typedef __attribute__((ext_vector_type(8))) short bf16x8;
typedef __attribute__((ext_vector_type(4))) float f32x4;

__device__ __forceinline__ float b2f(u16 h) {
    u32 u = ((u32)h) << 16;
    return __uint_as_float(u);
}
__device__ __forceinline__ u16 f2b(float f) {
    u32 u = __float_as_uint(f);
    u32 r = (u + 0x7fffu + ((u >> 16) & 1u)) >> 16;
    return (u16)r;
}

// ---------------- first linear: x = x_in @ w_first + b_first (bf16 out, 8 c/thread) ----------------
__global__ __launch_bounds__(256) void first_linear_kern(
    const float* __restrict__ x_in, const float* __restrict__ w,
    const float* __restrict__ bias, u16* __restrict__ xout, int M)
{
    __shared__ float sw[6 * 128];
    __shared__ float sb[128];
    int t = threadIdx.x;
    for (int i = t; i < 768; i += 256) sw[i] = w[i];
    if (t < 128) sb[t] = bias[t];
    __syncthreads();
    int idx = blockIdx.x * 256 + t;   // = row*16 + cg
    int row = idx >> 4;
    int cg = (idx & 15) * 8;
    if (row >= M) return;
    const float* xr = x_in + (size_t)row * 6;
    float xv[6];
#pragma unroll
    for (int j = 0; j < 6; j++) xv[j] = xr[j];
    float acc[8];
#pragma unroll
    for (int i = 0; i < 8; i++) acc[i] = sb[cg + i];
#pragma unroll
    for (int j = 0; j < 6; j++)
#pragma unroll
        for (int i = 0; i < 8; i++) acc[i] += xv[j] * sw[j * 128 + cg + i];
    ushort4 h0, h1;
    h0.x = f2b(acc[0]); h0.y = f2b(acc[1]); h0.z = f2b(acc[2]); h0.w = f2b(acc[3]);
    h1.x = f2b(acc[4]); h1.y = f2b(acc[5]); h1.z = f2b(acc[6]); h1.w = f2b(acc[7]);
    uint4 pk;
    pk.x = (u32)h0.x | ((u32)h0.y << 16);
    pk.y = (u32)h0.z | ((u32)h0.w << 16);
    pk.z = (u32)h1.x | ((u32)h1.y << 16);
    pk.w = (u32)h1.z | ((u32)h1.w << 16);
    *(uint4*)(xout + (size_t)row * 128 + cg) = pk;
}

// ------------- weight pack: dst[n][k] = bf16(src[k][n]), per block i = blockIdx.z -------------
__global__ __launch_bounds__(256) void pack_w_kern(
    const float* __restrict__ src, u16* __restrict__ dst, int K)
{
    int i = blockIdx.z;
    src += (size_t)i * K * 128;
    dst += (size_t)i * K * 128;
    int idx = blockIdx.x * 256 + threadIdx.x;  // = n*K + k
    int n = idx / K;
    int k = idx % K;
    dst[idx] = f2b(src[(size_t)k * 128 + n]);
}

// ------------- rotation weight pack: WR1[n][k256] = [Are; -Aim]^T, WR2 = [Are; Aim]^T -------------
__global__ __launch_bounds__(256) void pack_rot_kern(
    const float* __restrict__ Are, const float* __restrict__ Aim,
    u16* __restrict__ WR1, u16* __restrict__ WR2)
{
    int i = blockIdx.z;
    const float* are = Are + (size_t)i * 16384;
    const float* aim = Aim + (size_t)i * 16384;
    int idx = blockIdx.x * 256 + threadIdx.x;  // 0..32767 = n*256 + k
    int n = idx >> 8;
    int k = idx & 255;
    float v1, v2;
    if (k < 128) { float a = are[(size_t)k * 128 + n]; v1 = a; v2 = a; }
    else         { float a = aim[(size_t)(k - 128) * 128 + n]; v1 = -a; v2 = a; }
    WR1[(size_t)i * 32768 + idx] = f2b(v1);
    WR2[(size_t)i * 32768 + idx] = f2b(v2);
}

// ------------- CSR build: histogram -> 3-phase parallel scan -> scatter idx -> gather vals -------------
__global__ __launch_bounds__(256) void hist_kern(const int* __restrict__ rows, int* count)
{
    int e = blockIdx.x * 256 + threadIdx.x;
    if (e < E_) atomicAdd(&count[rows[e]], 1);
}

// inclusive scan across a 256-thread block (4 waves, shfl-based)
__device__ __forceinline__ int block_incl_scan_256(int v, int t)
{
    __shared__ int wsum[4];
    int lane = t & 63;
    int wid = t >> 6;
    int x = v;
#pragma unroll
    for (int off = 1; off < 64; off <<= 1) {
        int y = __shfl_up(x, off);
        if (lane >= off) x += y;
    }
    if (lane == 63) wsum[wid] = x;
    __syncthreads();
    if (t == 0) {
        int s = 0;
#pragma unroll
        for (int i = 0; i < 4; i++) { int tm = wsum[i]; wsum[i] = s; s += tm; }
    }
    __syncthreads();
    return x + wsum[wid];
}

// phase 1: per-block exclusive scan of counts -> rowptr (partial), block totals
__global__ __launch_bounds__(256) void scan1_kern(
    const int* __restrict__ count, int* __restrict__ excl_out,
    int* __restrict__ blockTotals)
{
    int t = threadIdx.x;
    int g = blockIdx.x * 256 + t;
    int v = (g < N_) ? count[g] : 0;
    int incl = block_incl_scan_256(v, t);
    if (g < N_) excl_out[g] = incl - v;
    if (t == 255) blockTotals[blockIdx.x] = incl;
}

// phase 2: single-block scan of 157 block totals -> exclusive block offsets + grand total
__global__ __launch_bounds__(256) void scan2_kern(
    const int* __restrict__ blockTotals, int* __restrict__ blockOffs,
    int* __restrict__ totalOut)
{
    int t = threadIdx.x;
    int v = (t < NB_SCAN) ? blockTotals[t] : 0;
    int incl = block_incl_scan_256(v, t);
    if (t < NB_SCAN) blockOffs[t] = incl - v;
    if (t == 255) *totalOut = incl;   // = E_, written to rowptr[N_]
}

// phase 3: add block offsets; materialize rowptr + nextp cursors
__global__ __launch_bounds__(256) void scan3_kern(
    int* __restrict__ rowptr, int* __restrict__ nextp,
    const int* __restrict__ blockOffs)
{
    int t = threadIdx.x;
    int g = blockIdx.x * 256 + t;
    if (g >= N_) return;
    int v = rowptr[g] + blockOffs[blockIdx.x];
    rowptr[g] = v;
    nextp[g] = v;
}

// scatter only indices (2 scattered u32 writes per edge)
__global__ __launch_bounds__(256) void scatter_idx_kern(
    const int* __restrict__ rows, const int* __restrict__ cols,
    int* nextp, int* __restrict__ scols, int* __restrict__ sperm)
{
    int e = blockIdx.x * 256 + threadIdx.x;
    if (e >= E_) return;
    int r = rows[e];
    int pos = atomicAdd(&nextp[r], 1);
    scols[pos] = cols[e];
    sperm[pos] = e;
}

// gather values: coalesced writes, L2-cached random reads
__global__ __launch_bounds__(256) void gather_vals_kern(
    const int* __restrict__ sperm,
    const float* __restrict__ gvx, const float* __restrict__ gvy,
    float* __restrict__ svx, float* __restrict__ svy)
{
    int pos = blockIdx.x * 256 + threadIdx.x;
    if (pos >= E_) return;
    int e = sperm[pos];
#pragma unroll
    for (int b = 0; b < B_; b++) {
        svx[(size_t)b * E_ + pos] = gvx[(size_t)b * E_ + e];
        svy[(size_t)b * E_ + pos] = gvy[(size_t)b * E_ + e];
    }
}

// ------------- CSR dual spMM (single batch), bf16 packed out, edge-unrolled x2 -------------
__global__ __launch_bounds__(256) void spmm_csr_kern(
    const int* __restrict__ rowptr, const int* __restrict__ scols,
    const float* __restrict__ svx, const float* __restrict__ svy,
    const u16* __restrict__ xd_b, u16* __restrict__ gXh, u16* __restrict__ gYh)
{
    int t = threadIdx.x;
    int r = blockIdx.x * 4 + (t >> 6);
    int c2 = (t & 63) * 2;
    int beg = rowptr[r], end = rowptr[r + 1];
    float ax0 = 0.f, ax1 = 0.f, ay0 = 0.f, ay1 = 0.f;
    int j = beg;
    for (; j + 1 < end; j += 2) {
        int ca = scols[j], cb = scols[j + 1];
        u32 xwa = *(const u32*)(xd_b + (size_t)ca * 128 + c2);
        u32 xwb = *(const u32*)(xd_b + (size_t)cb * 128 + c2);
        float vxa = svx[j], vya = svy[j];
        float vxb = svx[j + 1], vyb = svy[j + 1];
        float xa0 = b2f((u16)(xwa & 0xffffu)), xa1 = b2f((u16)(xwa >> 16));
        float xb0 = b2f((u16)(xwb & 0xffffu)), xb1 = b2f((u16)(xwb >> 16));
        ax0 += vxa * xa0; ax1 += vxa * xa1;
        ay0 += vya * xa0; ay1 += vya * xa1;
        ax0 += vxb * xb0; ax1 += vxb * xb1;
        ay0 += vyb * xb0; ay1 += vyb * xb1;
    }
    if (j < end) {
        int col = scols[j];
        u32 xw = *(const u32*)(xd_b + (size_t)col * 128 + c2);
        float x0 = b2f((u16)(xw & 0xffffu));
        float x1 = b2f((u16)(xw >> 16));
        float vx = svx[j], vy = svy[j];
        ax0 += vx * x0; ax1 += vx * x1;
        ay0 += vy * x0; ay1 += vy * x1;
    }
    u32 px = (u32)f2b(ax0) | ((u32)f2b(ax1) << 16);
    u32 py = (u32)f2b(ay0) | ((u32)f2b(ay1) << 16);
    *(u32*)(gXh + (size_t)r * 128 + c2) = px;
    *(u32*)(gYh + (size_t)r * 128 + c2) = py;
}

// ------------- spectral projection stage 1: MFMA over transposed LDS tiles -------------
__global__ __launch_bounds__(256) void spec_stage1_mfma_kern(
    const u16* __restrict__ x, const float* __restrict__ mass,
    const float* __restrict__ evecs, float* __restrict__ partials)
{
    __shared__ __align__(16) u16 sEVh[128][40];
    __shared__ __align__(16) u16 sEVl[128][40];
    __shared__ __align__(16) u16 sXM[128][40];
    int b = blockIdx.y;
    int pb = blockIdx.x;
    const u16* xb = x + (size_t)b * N_ * 128;
    const float* mb = mass + (size_t)b * N_;
    const float* eb = evecs + (size_t)b * N_ * 128;
    float* dst = partials + ((size_t)b * 128 + pb) * 16384;

    int t = threadIdx.x;
    int wv = t >> 6;
    int lane = t & 63;
    int quad = lane >> 4;
    int r16 = lane & 15;
    int kb = wv * 32;
    int kc = (t & 63) * 2;
    int nh = wv;

    f32x4 acc[2][8];
#pragma unroll
    for (int i = 0; i < 2; i++)
#pragma unroll
        for (int j = 0; j < 8; j++) acc[i][j] = (f32x4){0.f, 0.f, 0.f, 0.f};

    for (int ch = pb; ch < N_ / 32; ch += 128) {
        int nbase = ch * 32 + nh * 8;
        float4 m0 = *(const float4*)(mb + nbase);
        float4 m1 = *(const float4*)(mb + nbase + 4);
        float mm[8] = {m0.x, m0.y, m0.z, m0.w, m1.x, m1.y, m1.z, m1.w};
        u32 eh0[4], eh1[4], el0[4], el1[4], xq0[4], xq1[4];
#pragma unroll
        for (int jp = 0; jp < 4; jp++) {
            eh0[jp] = 0; eh1[jp] = 0; el0[jp] = 0;
            el1[jp] = 0; xq0[jp] = 0; xq1[jp] = 0;
        }
#pragma unroll
        for (int j = 0; j < 8; j++) {
            float2 e = *(const float2*)(eb + (size_t)(nbase + j) * 128 + kc);
            u32 xw = *(const u32*)(xb + (size_t)(nbase + j) * 128 + kc);
            u16 h0 = f2b(e.x);
            u16 h1 = f2b(e.y);
            u16 l0 = f2b(e.x - b2f(h0));
            u16 l1 = f2b(e.y - b2f(h1));
            u16 q0 = f2b(b2f((u16)(xw & 0xffffu)) * mm[j]);
            u16 q1 = f2b(b2f((u16)(xw >> 16)) * mm[j]);
            int sh = (j & 1) * 16;
            int jp = j >> 1;
            eh0[jp] |= ((u32)h0) << sh; eh1[jp] |= ((u32)h1) << sh;
            el0[jp] |= ((u32)l0) << sh; el1[jp] |= ((u32)l1) << sh;
            xq0[jp] |= ((u32)q0) << sh; xq1[jp] |= ((u32)q1) << sh;
        }
        __syncthreads();
        *(uint4*)&sEVh[kc][nh * 8]     = make_uint4(eh0[0], eh0[1], eh0[2], eh0[3]);
        *(uint4*)&sEVh[kc + 1][nh * 8] = make_uint4(eh1[0], eh1[1], eh1[2], eh1[3]);
        *(uint4*)&sEVl[kc][nh * 8]     = make_uint4(el0[0], el0[1], el0[2], el0[3]);
        *(uint4*)&sEVl[kc + 1][nh * 8] = make_uint4(el1[0], el1[1], el1[2], el1[3]);
        *(uint4*)&sXM[kc][nh * 8]      = make_uint4(xq0[0], xq0[1], xq0[2], xq0[3]);
        *(uint4*)&sXM[kc + 1][nh * 8]  = make_uint4(xq1[0], xq1[1], xq1[2], xq1[3]);
        __syncthreads();

        bf16x8 ah0 = *(const bf16x8*)&sEVh[kb + r16][quad * 8];
        bf16x8 ah1 = *(const bf16x8*)&sEVh[kb + 16 + r16][quad * 8];
        bf16x8 al0 = *(const bf16x8*)&sEVl[kb + r16][quad * 8];
        bf16x8 al1 = *(const bf16x8*)&sEVl[kb + 16 + r16][quad * 8];
#pragma unroll
        for (int nt = 0; nt < 8; nt++) {
            bf16x8 bx = *(const bf16x8*)&sXM[nt * 16 + r16][quad * 8];
            acc[0][nt] = __builtin_amdgcn_mfma_f32_16x16x32_bf16(ah0, bx, acc[0][nt], 0, 0, 0);
            acc[1][nt] = __builtin_amdgcn_mfma_f32_16x16x32_bf16(ah1, bx, acc[1][nt], 0, 0, 0);
            acc[0][nt] = __builtin_amdgcn_mfma_f32_16x16x32_bf16(al0, bx, acc[0][nt], 0, 0, 0);
            acc[1][nt] = __builtin_amdgcn_mfma_f32_16x16x32_bf16(al1, bx, acc[1][nt], 0, 0, 0);
        }
    }

#pragma unroll
    for (int mt = 0; mt < 2; mt++)
#pragma unroll
        for (int nt = 0; nt < 8; nt++)
#pragma unroll
            for (int reg = 0; reg < 4; reg++) {
                int kk = kb + mt * 16 + quad * 4 + reg;
                int cc = nt * 16 + r16;
                dst[(size_t)kk * 128 + cc] = acc[mt][nt][reg];
            }
}

// ------------- stage 2 + coefficients, TRANSPOSED bf16 out: ys_t[b][c][k] -------------
__global__ __launch_bounds__(128) void spec_stage2_coef_kern(
    const float* __restrict__ partials, const float* __restrict__ evals,
    const float* __restrict__ dt, u16* __restrict__ ys_t)
{
    int b = blockIdx.x >> 7;
    int k = blockIdx.x & 127;
    int c = threadIdx.x;
    const float* p = partials + (size_t)b * 128 * 16384 + (size_t)k * 128 + c;
    float s = 0.f;
#pragma unroll 8
    for (int pb = 0; pb < 128; pb++) s += p[(size_t)pb * 16384];
    float co = expf(-evals[b * 128 + k] * dt[c]);
    ys_t[((size_t)b * 128 + c) * 128 + k] = f2b(s * co);
}

// ------------- MFMA GEMM: out[m,0:128] = A[m,:KK] @ W (bf16 out); AF32 path for evecs ------
template <int KK, bool AF32>
__global__ __launch_bounds__(256) void mgemm_kern(
    const void* __restrict__ A0v,
    const u16* __restrict__ Wp, u16* __restrict__ outp,
    size_t aBatch, size_t wBatch, size_t oBatch)
{
    __shared__ u16 sA[64][72];
    __shared__ u16 sB[128][72];
    int z = blockIdx.z;
    const u16* Wb = Wp + wBatch * (size_t)z;
    size_t aOff = aBatch * (size_t)z;
    size_t oOff = oBatch * (size_t)z;

    int t = threadIdx.x;
    int m0 = blockIdx.x * 64;
    int wv = t >> 6;
    int lane = t & 63;
    int quad = lane >> 4;
    int r16 = lane & 15;
    int mw = (wv & 1) * 32;
    int nw = (wv >> 1) * 64;

    f32x4 acc[2][4];
#pragma unroll
    for (int i = 0; i < 2; i++)
#pragma unroll
        for (int j = 0; j < 4; j++) acc[i][j] = (f32x4){0.f, 0.f, 0.f, 0.f};

#pragma unroll 1
    for (int kt = 0; kt < KK / 64; kt++) {
        int kbase = kt * 64;
        __syncthreads();
        if (AF32) {
            const float* Af = (const float*)A0v + aOff;
#pragma unroll
            for (int p = 0; p < 4; p++) {
                int idx = p * 256 + t;
                int row = idx >> 4;
                int seg = idx & 15;
                float4 v = *(const float4*)(Af + (size_t)(m0 + row) * 128 + kbase + seg * 4);
                ushort4 h;
                h.x = f2b(v.x); h.y = f2b(v.y); h.z = f2b(v.z); h.w = f2b(v.w);
                *(ushort4*)&sA[row][seg * 4] = h;
            }
        } else {
            const u16* Ah = (const u16*)A0v + aOff;
#pragma unroll
            for (int p = 0; p < 2; p++) {
                int idx = p * 256 + t;
                int row = idx >> 3;
                int seg = idx & 7;
                *(uint4*)&sA[row][seg * 8] =
                    *(const uint4*)(Ah + (size_t)(m0 + row) * 128 + kbase + seg * 8);
            }
        }
        {
#pragma unroll
            for (int p = 0; p < 4; p++) {
                int idx = p * 256 + t;
                int n = idx >> 3;
                int seg = idx & 7;
                *(uint4*)&sB[n][seg * 8] =
                    *(const uint4*)(Wb + (size_t)n * KK + kbase + seg * 8);
            }
        }
        __syncthreads();

#pragma unroll
        for (int ks = 0; ks < 2; ks++) {
            int ko = ks * 32 + quad * 8;
            bf16x8 a0 = *(const bf16x8*)&sA[mw + r16][ko];
            bf16x8 a1 = *(const bf16x8*)&sA[mw + 16 + r16][ko];
            bf16x8 b0 = *(const bf16x8*)&sB[nw + r16][ko];
            bf16x8 b1 = *(const bf16x8*)&sB[nw + 16 + r16][ko];
            bf16x8 b2 = *(const bf16x8*)&sB[nw + 32 + r16][ko];
            bf16x8 b3 = *(const bf16x8*)&sB[nw + 48 + r16][ko];
            acc[0][0] = __builtin_amdgcn_mfma_f32_16x16x32_bf16(a0, b0, acc[0][0], 0, 0, 0);
            acc[0][1] = __builtin_amdgcn_mfma_f32_16x16x32_bf16(a0, b1, acc[0][1], 0, 0, 0);
            acc[0][2] = __builtin_amdgcn_mfma_f32_16x16x32_bf16(a0, b2, acc[0][2], 0, 0, 0);
            acc[0][3] = __builtin_amdgcn_mfma_f32_16x16x32_bf16(a0, b3, acc[0][3], 0, 0, 0);
            acc[1][0] = __builtin_amdgcn_mfma_f32_16x16x32_bf16(a1, b0, acc[1][0], 0, 0, 0);
            acc[1][1] = __builtin_amdgcn_mfma_f32_16x16x32_bf16(a1, b1, acc[1][1], 0, 0, 0);
            acc[1][2] = __builtin_amdgcn_mfma_f32_16x16x32_bf16(a1, b2, acc[1][2], 0, 0, 0);
            acc[1][3] = __builtin_amdgcn_mfma_f32_16x16x32_bf16(a1, b3, acc[1][3], 0, 0, 0);
        }
    }

#pragma unroll
    for (int nt = 0; nt < 4; nt++) {
        int col = nw + nt * 16 + r16;
#pragma unroll
        for (int mt = 0; mt < 2; mt++) {
#pragma unroll
            for (int reg = 0; reg < 4; reg++) {
                int row = m0 + mw + mt * 16 + quad * 4 + reg;
                outp[oOff + (size_t)row * 128 + col] = f2b(acc[mt][nt][reg]);
            }
        }
    }
}

// ------------- FUSED rotation + tanh + 3-layer MiniMLP (per batch-pair via z) -------------
// LDS plan (80 KB, 2 blocks/CU):
//   sGX/sGY [64][136]: gX/gY tiles; gf overwrites sGX in-place after tanh
//   sB [128][72]: WR1 chunk, then W0/W1/W2 chunks
//   sHbuf: WR2 chunk as [128][72] view, then h1/h2 as [64][152] view
//   sA [64][72]: x/xd staging for MLP stage0 k-chunks 0-3
__global__ __launch_bounds__(256) void mlp_rot_fused_kern(
    const u16* __restrict__ xg, const u16* __restrict__ xdg,
    const u16* __restrict__ gXY,
    const u16* __restrict__ WR1, const u16* __restrict__ WR2,
    const u16* __restrict__ W0, const u16* __restrict__ W1, const u16* __restrict__ W2,
    const float* __restrict__ b0, const float* __restrict__ b1, const float* __restrict__ b2,
    int batch0, u16* __restrict__ outp)
{
    __shared__ u16 sGX[64][136];
    __shared__ u16 sGY[64][136];
    __shared__ u16 sB[128][72];
    __shared__ __align__(16) u16 sHbuf[9728];   // 19456 B
    __shared__ u16 sA[64][72];
#define HV(r, c) sHbuf[(r) * 152 + (c)]
#define WV(n, c) sHbuf[(n) * 72 + (c)]

    const size_t NZ = (size_t)N_ * 128;
    int z = blockIdx.z;
    int batch = batch0 + z;
    const u16* gX = gXY + (size_t)z * 2 * NZ;
    const u16* gY = gX + NZ;
    int m0n = blockIdx.x * 64;
    size_t growBase = ((size_t)batch * N_ + m0n) * 128;

    int t = threadIdx.x;
    int wv = t >> 6;
    int lane = t & 63;
    int quad = lane >> 4;
    int r16 = lane & 15;
    int mw = (wv & 1) * 32;
    int nw = (wv >> 1) * 64;

    // ---- stage gX, gY tiles ----
#pragma unroll
    for (int p = 0; p < 4; p++) {
        int idx = p * 256 + t;
        int row = idx >> 4;
        int seg = idx & 15;
        *(uint4*)&sGX[row][seg * 8] = *(const uint4*)(gX + (size_t)(m0n + row) * 128 + seg * 8);
        *(uint4*)&sGY[row][seg * 8] = *(const uint4*)(gY + (size_t)(m0n + row) * 128 + seg * 8);
    }

    f32x4 accRe[2][4], accIm[2][4];
#pragma unroll
    for (int i = 0; i < 2; i++)
#pragma unroll
        for (int j = 0; j < 4; j++) {
            accRe[i][j] = (f32x4){0.f, 0.f, 0.f, 0.f};
            accIm[i][j] = (f32x4){0.f, 0.f, 0.f, 0.f};
        }

    // ---- rotation: 4 x 64-k chunks; WR1 -> sB, WR2 -> sHbuf view ----
#pragma unroll 1
    for (int c = 0; c < 4; c++) {
        __syncthreads();   // c=0 also covers sGX/sGY staging
#pragma unroll
        for (int p = 0; p < 4; p++) {
            int idx = p * 256 + t;
            int n = idx >> 3;
            int seg = idx & 7;
            *(uint4*)&sB[n][seg * 8] = *(const uint4*)(WR1 + (size_t)n * 256 + c * 64 + seg * 8);
            *(uint4*)&WV(n, seg * 8) = *(const uint4*)(WR2 + (size_t)n * 256 + c * 64 + seg * 8);
        }
        __syncthreads();

        const u16 (*sRe)[136] = (c < 2) ? sGX : sGY;
        const u16 (*sIm)[136] = (c < 2) ? sGY : sGX;
        int kob = (c & 1) * 64;
#pragma unroll
        for (int ks = 0; ks < 2; ks++) {
            int ko = kob + ks * 32 + quad * 8;
            int kb = ks * 32 + quad * 8;
            bf16x8 aRe0 = *(const bf16x8*)&sRe[mw + r16][ko];
            bf16x8 aRe1 = *(const bf16x8*)&sRe[mw + 16 + r16][ko];
            bf16x8 aIm0 = *(const bf16x8*)&sIm[mw + r16][ko];
            bf16x8 aIm1 = *(const bf16x8*)&sIm[mw + 16 + r16][ko];
#pragma unroll
            for (int j = 0; j < 4; j++) {
                bf16x8 w1f = *(const bf16x8*)&sB[nw + 16 * j + r16][kb];
                bf16x8 w2f = *(const bf16x8*)&WV(nw + 16 * j + r16, kb);
                accRe[0][j] = __builtin_amdgcn_mfma_f32_16x16x32_bf16(aRe0, w1f, accRe[0][j], 0, 0, 0);
                accRe[1][j] = __builtin_amdgcn_mfma_f32_16x16x32_bf16(aRe1, w1f, accRe[1][j], 0, 0, 0);
                accIm[0][j] = __builtin_amdgcn_mfma_f32_16x16x32_bf16(aIm0, w2f, accIm[0][j], 0, 0, 0);
                accIm[1][j] = __builtin_amdgcn_mfma_f32_16x16x32_bf16(aIm1, w2f, accIm[1][j], 0, 0, 0);
            }
        }
    }

    // ---- tanh in place: gf -> sGX (each element owned by exactly one lane) ----
    __syncthreads();   // all fragment reads of sGX/sGY complete
#pragma unroll
    for (int nt = 0; nt < 4; nt++) {
        int col = nw + nt * 16 + r16;
#pragma unroll
        for (int mt = 0; mt < 2; mt++)
#pragma unroll
            for (int reg = 0; reg < 4; reg++) {
                int lrow = mw + mt * 16 + quad * 4 + reg;
                float gx = b2f(sGX[lrow][col]);
                float gy = b2f(sGY[lrow][col]);
                float v = tanhf(gx * accRe[mt][nt][reg] + gy * accIm[mt][nt][reg]);
                sGX[lrow][col] = f2b(v);
            }
    }

    // ---- MLP stage 0: K=384 over concat(x, xd, gf-from-LDS) ----
    f32x4 acc[2][4];
#pragma unroll
    for (int i = 0; i < 2; i++)
#pragma unroll
        for (int j = 0; j < 4; j++) acc[i][j] = (f32x4){0.f, 0.f, 0.f, 0.f};
#pragma unroll 1
    for (int kt = 0; kt < 6; kt++) {
        int kbase = kt * 64;
        int kloc = kbase & 127;
        __syncthreads();   // kt=0 covers tanh writes; also protects sA/sB reuse
        if (kt < 4) {
            const u16* Ap = (kt < 2) ? xg : xdg;
#pragma unroll
            for (int p = 0; p < 2; p++) {
                int idx = p * 256 + t;
                int row = idx >> 3;
                int seg = idx & 7;
                *(uint4*)&sA[row][seg * 8] =
                    *(const uint4*)(Ap + growBase + (size_t)row * 128 + kloc + seg * 8);
            }
        }
#pragma unroll
        for (int p = 0; p < 4; p++) {
            int idx = p * 256 + t;
            int n = idx >> 3;
            int seg = idx & 7;
            *(uint4*)&sB[n][seg * 8] = *(const uint4*)(W0 + (size_t)n * 384 + kbase + seg * 8);
        }
        __syncthreads();
#pragma unroll
        for (int ks = 0; ks < 2; ks++) {
            int ko = ks * 32 + quad * 8;
            bf16x8 a0, a1;
            if (kt < 4) {
                a0 = *(const bf16x8*)&sA[mw + r16][ko];
                a1 = *(const bf16x8*)&sA[mw + 16 + r16][ko];
            } else {
                a0 = *(const bf16x8*)&sGX[mw + r16][kloc + ko];
                a1 = *(const bf16x8*)&sGX[mw + 16 + r16][kloc + ko];
            }
#pragma unroll
            for (int j = 0; j < 4; j++) {
                bf16x8 bj = *(const bf16x8*)&sB[nw + 16 * j + r16][ko];
                acc[0][j] = __builtin_amdgcn_mfma_f32_16x16x32_bf16(a0, bj, acc[0][j], 0, 0, 0);
                acc[1][j] = __builtin_amdgcn_mfma_f32_16x16x32_bf16(a1, bj, acc[1][j], 0, 0, 0);
            }
        }
    }
    // h1 -> sH (bias + relu + bf16); sHbuf free (WR2 chunks consumed)
    __syncthreads();   // all waves done reading WR2 view (last rotation use was long ago, but sB race too)
#pragma unroll
    for (int nt = 0; nt < 4; nt++) {
        int col = nw + nt * 16 + r16;
        float bv = b0[col];
#pragma unroll
        for (int mt = 0; mt < 2; mt++)
#pragma unroll
            for (int reg = 0; reg < 4; reg++) {
                int rl = mw + mt * 16 + quad * 4 + reg;
                HV(rl, col) = f2b(fmaxf(acc[mt][nt][reg] + bv, 0.f));
            }
    }

    // ---- stage 1: h2 = relu(h1 @ W1 + b1) ----
#pragma unroll
    for (int i = 0; i < 2; i++)
#pragma unroll
        for (int j = 0; j < 4; j++) acc[i][j] = (f32x4){0.f, 0.f, 0.f, 0.f};
#pragma unroll 1
    for (int kt = 0; kt < 2; kt++) {
        int kbase = kt * 64;
        __syncthreads();   // kt=0 covers h1 writes
#pragma unroll
        for (int p = 0; p < 4; p++) {
            int idx = p * 256 + t;
            int n = idx >> 3;
            int seg = idx & 7;
            *(uint4*)&sB[n][seg * 8] = *(const uint4*)(W1 + (size_t)n * 128 + kbase + seg * 8);
        }
        __syncthreads();
#pragma unroll
        for (int ks = 0; ks < 2; ks++) {
            int ko = kbase + ks * 32 + quad * 8;
            int kb = ks * 32 + quad * 8;
            bf16x8 a0 = *(const bf16x8*)&HV(mw + r16, ko);
            bf16x8 a1 = *(const bf16x8*)&HV(mw + 16 + r16, ko);
#pragma unroll
            for (int j = 0; j < 4; j++) {
                bf16x8 bj = *(const bf16x8*)&sB[nw + 16 * j + r16][kb];
                acc[0][j] = __builtin_amdgcn_mfma_f32_16x16x32_bf16(a0, bj, acc[0][j], 0, 0, 0);
                acc[1][j] = __builtin_amdgcn_mfma_f32_16x16x32_bf16(a1, bj, acc[1][j], 0, 0, 0);
            }
        }
    }
    __syncthreads();   // all waves done reading h1
#pragma unroll
    for (int nt = 0; nt < 4; nt++) {
        int col = nw + nt * 16 + r16;
        float bv = b1[col];
#pragma unroll
        for (int mt = 0; mt < 2; mt++)
#pragma unroll
            for (int reg = 0; reg < 4; reg++) {
                int rl = mw + mt * 16 + quad * 4 + reg;
                HV(rl, col) = f2b(fmaxf(acc[mt][nt][reg] + bv, 0.f));
            }
    }

    // ---- stage 2: out = h2 @ W2 + b2 + resid(x) ----
#pragma unroll
    for (int i = 0; i < 2; i++)
#pragma unroll
        for (int j = 0; j < 4; j++) acc[i][j] = (f32x4){0.f, 0.f, 0.f, 0.f};
#pragma unroll 1
    for (int kt = 0; kt < 2; kt++) {
        int kbase = kt * 64;
        __syncthreads();   // kt=0 covers h2 writes
#pragma unroll
        for (int p = 0; p < 4; p++) {
            int idx = p * 256 + t;
            int n = idx >> 3;
            int seg = idx & 7;
            *(uint4*)&sB[n][seg * 8] = *(const uint4*)(W2 + (size_t)n * 128 + kbase + seg * 8);
        }
        __syncthreads();
#pragma unroll
        for (int ks = 0; ks < 2; ks++) {
            int ko = kbase + ks * 32 + quad * 8;
            int kb = ks * 32 + quad * 8;
            bf16x8 a0 = *(const bf16x8*)&HV(mw + r16, ko);
            bf16x8 a1 = *(const bf16x8*)&HV(mw + 16 + r16, ko);
#pragma unroll
            for (int j = 0; j < 4; j++) {
                bf16x8 bj = *(const bf16x8*)&sB[nw + 16 * j + r16][kb];
                acc[0][j] = __builtin_amdgcn_mfma_f32_16x16x32_bf16(a0, bj, acc[0][j], 0, 0, 0);
                acc[1][j] = __builtin_amdgcn_mfma_f32_16x16x32_bf16(a1, bj, acc[1][j], 0, 0, 0);
            }
        }
    }
#pragma unroll
    for (int nt = 0; nt < 4; nt++) {
        int col = nw + nt * 16 + r16;
        float bv = b2[col];
#pragma unroll
        for (int mt = 0; mt < 2; mt++)
#pragma unroll
            for (int reg = 0; reg < 4; reg++) {
                int row = mw + mt * 16 + quad * 4 + reg;
                float v = acc[mt][nt][reg] + bv + b2f(xg[growBase + (size_t)row * 128 + col]);
                outp[growBase + (size_t)row * 128 + col] = f2b(v);
            }
    }
#undef HV
#undef WV
}

// ------------- last linear: out[m,0:3] = x[m,:] @ w_last + b_last -------------
__global__ __launch_bounds__(256) void last_linear_kern(
    const u16* __restrict__ x, const float* __restrict__ w,
    const float* __restrict__ bias, float* __restrict__ outp, int M)
{
    __shared__ float sw[128 * 3];
    int t = threadIdx.x;
    for (int i = t; i < 384; i += 256) sw[i] = w[i];
    __syncthreads();
    int wave = t >> 6;
    int lane = t & 63;
    int row = blockIdx.x * 4 + wave;
    if (row >= M) return;
    const u16* xr = x + (size_t)row * 128;
    float p0 = 0.f, p1 = 0.f, p2 = 0.f;
#pragma unroll
    for (int h = 0; h < 2; h++) {
        int c = lane + h * 64;
        float xv = b2f(xr[c]);
        p0 += xv * sw[c * 3 + 0];
        p1 += xv * sw[c * 3 + 1];
        p2 += xv * sw[c * 3 + 2];
    }
#pragma unroll
    for (int off = 32; off > 0; off >>= 1) {
        p0 += __shfl_xor(p0, off);
        p1 += __shfl_xor(p1, off);
        p2 += __shfl_xor(p2, off);
    }
    if (lane == 0) {
        float* o = outp + (size_t)row * 3;
        o[0] = p0 + bias[0];
        o[1] = p1 + bias[1];
        o[2] = p2 + bias[2];
    }
}

extern "C" void kernel_launch(void* const* d_in, const int* in_sizes, int n_in,
                              void* d_out, int out_size, void* d_ws, size_t ws_size,
                              hipStream_t stream)
{
    const float* x_in    = (const float*)d_in[0];
    const float* mass    = (const float*)d_in[1];
    const float* evals   = (const float*)d_in[2];
    const float* evecs   = (const float*)d_in[3];
    const int*   rows    = (const int*)  d_in[4];
    const int*   cols    = (const int*)  d_in[5];
    const float* gvx     = (const float*)d_in[6];
    const float* gvy     = (const float*)d_in[7];
    const float* w_first = (const float*)d_in[8];
    const float* b_first = (const float*)d_in[9];
    const float* dtimes  = (const float*)d_in[10];
    const float* A_re    = (const float*)d_in[11];
    const float* A_im    = (const float*)d_in[12];
    const float* w0      = (const float*)d_in[13];
    const float* b0      = (const float*)d_in[14];
    const float* w1      = (const float*)d_in[15];
    const float* b1      = (const float*)d_in[16];
    const float* w2      = (const float*)d_in[17];
    const float* b2      = (const float*)d_in[18];
    const float* w_last  = (const float*)d_in[19];
    const float* b_last  = (const float*)d_in[20];
    float* outp = (float*)d_out;

    const size_t SZ = (size_t)B_ * N_ * 128;   // 20,480,000 elements
    const size_t NZ = (size_t)N_ * 128;        //  5,120,000 elements

    // workspace layout (~174 MB)
    u16* P0 = (u16*)d_ws;                      // 41 MB  (x ping-pong)
    u16* P1 = P0 + SZ;                         // 41 MB  (xd ping-pong)
    u16* GF = P1 + SZ;                         // 41 MB  (gX/gY scratch, 2 batch slots)
    float* SC = (float*)(GF + SZ);             // 41 MB  f32: spec partials / scan scratch
    u16* ys_t = (u16*)(SC + 8388608);          // 128 KB inside SC tail
    u16* WP0 = (u16*)(SC + 2 * NZ);            // packed transposed bf16 weights
    u16* WP1 = WP0 + 4 * 49152;
    u16* WP2 = WP1 + 4 * 16384;
    u16* WR1 = WP2 + 4 * 16384;                // 4 x [128][256] rotation packs
    u16* WR2 = WR1 + 4 * 32768;
    int* rowptr = (int*)(WR2 + 4 * 32768);     // N+1 (padded to 40004)
    int* nextp  = rowptr + 40004;              // N (histogram counts, then cursors)
    int* scols  = nextp + N_;                  // E sorted cols
    float* svx  = (float*)(scols + E_);        // [B][E] sorted vals
    float* svy  = svx + (size_t)B_ * E_;

    u16* x  = P0;
    u16* xd = P1;
    const int M = B_ * N_;                     // 160000

    // --- CSR build (pattern shared across blocks & X/Y) ---
    int* bTot  = (int*)SC;          // NB_SCAN block totals
    int* bOff  = bTot + 512;        // NB_SCAN block offsets
    int* sperm = bTot + 1024;       // E edge permutation (transient)
    hipMemsetAsync(nextp, 0, N_ * sizeof(int), stream);
    hist_kern<<<dim3((E_ + 255) / 256), 256, 0, stream>>>(rows, nextp);
    scan1_kern<<<dim3(NB_SCAN), 256, 0, stream>>>(nextp, rowptr, bTot);
    scan2_kern<<<dim3(1), 256, 0, stream>>>(bTot, bOff, rowptr + N_);
    scan3_kern<<<dim3(NB_SCAN), 256, 0, stream>>>(rowptr, nextp, bOff);
    scatter_idx_kern<<<dim3((E_ + 255) / 256), 256, 0, stream>>>(
        rows, cols, nextp, scols, sperm);
    gather_vals_kern<<<dim3((E_ + 255) / 256), 256, 0, stream>>>(
        sperm, gvx, gvy, svx, svy);

    // --- weight packing (once per launch) ---
    pack_w_kern<<<dim3(192, 1, 4), 256, 0, stream>>>(w0, WP0, 384);
    pack_w_kern<<<dim3(64, 1, 4), 256, 0, stream>>>(w1, WP1, 128);
    pack_w_kern<<<dim3(64, 1, 4), 256, 0, stream>>>(w2, WP2, 128);
    pack_rot_kern<<<dim3(128, 1, 4), 256, 0, stream>>>(A_re, A_im, WR1, WR2);

    first_linear_kern<<<dim3(M * 16 / 256), 256, 0, stream>>>(x_in, w_first, b_first, x, M);

    // gX/gY batch-pair scratch in GF: slot z holds gX at z*2*NZ, gY at z*2*NZ+NZ
    u16* GXY = GF;

    for (int i = 0; i < 4; i++) {
        // --- spectral diffusion ---
        spec_stage1_mfma_kern<<<dim3(128, B_), 256, 0, stream>>>(x, mass, evecs, SC);
        spec_stage2_coef_kern<<<dim3(B_ * 128), 128, 0, stream>>>(
            SC, evals, dtimes + (size_t)i * 128, ys_t);
        mgemm_kern<128, true><<<dim3(N_ / 64, 1, B_), 256, 0, stream>>>(
            evecs, ys_t, xd, NZ, (size_t)128 * 128, NZ);
        // --- per batch-pair: sparse gradients then fused rotate+tanh+MLP ---
        for (int p = 0; p < 2; p++) {
            for (int zz = 0; zz < 2; zz++) {
                int b = p * 2 + zz;
                spmm_csr_kern<<<dim3(N_ / 4), 256, 0, stream>>>(
                    rowptr, scols, svx + (size_t)b * E_, svy + (size_t)b * E_,
                    xd + (size_t)b * NZ,
                    GXY + (size_t)zz * 2 * NZ, GXY + (size_t)zz * 2 * NZ + NZ);
            }
            mlp_rot_fused_kern<<<dim3(N_ / 64, 1, 2), 256, 0, stream>>>(
                x, xd, GXY,
                WR1 + (size_t)i * 32768, WR2 + (size_t)i * 32768,
                WP0 + (size_t)i * 49152, WP1 + (size_t)i * 16384, WP2 + (size_t)i * 16384,
                b0 + (size_t)i * 128, b1 + (size_t)i * 128, b2 + (size_t)i * 128,
                p * 2, xd);
        }
        u16* tmp = x; x = xd; xd = tmp;
    }

    last_linear_kern<<<dim3(M / 4), 256, 0, stream>>>(x, w_last, b_last, outp, M);
}

// Round 7
// 1214.006 us; speedup vs baseline: 1.7453x; 1.1249x over previous
//
#include <hip/hip_runtime.h>

#define B_ 4
#define N_ 40000
#define E_ 240000
#define NB_SCAN ((N_ + 255) / 256)   // 157 scan blocks

typedef unsigned short u16;
typedef unsigned int u32;
typedef __attribute__((ext_vector_type(8))) short bf16x8;
typedef __attribute__((ext_vector_type(4))) float f32x4;

__device__ __forceinline__ float b2f(u16 h) {
    u32 u = ((u32)h) << 16;
    return __uint_as_float(u);
}
__device__ __forceinline__ u16 f2b(float f) {
    u32 u = __float_as_uint(f);
    u32 r = (u + 0x7fffu + ((u >> 16) & 1u)) >> 16;
    return (u16)r;
}

// ---------------- first linear: x = x_in @ w_first + b_first (bf16 out, 8 c/thread) ----------------
__global__ __launch_bounds__(256) void first_linear_kern(
    const float* __restrict__ x_in, const float* __restrict__ w,
    const float* __restrict__ bias, u16* __restrict__ xout, int M)
{
    __shared__ float sw[6 * 128];
    __shared__ float sb[128];
    int t = threadIdx.x;
    for (int i = t; i < 768; i += 256) sw[i] = w[i];
    if (t < 128) sb[t] = bias[t];
    __syncthreads();
    int idx = blockIdx.x * 256 + t;   // = row*16 + cg
    int row = idx >> 4;
    int cg = (idx & 15) * 8;
    if (row >= M) return;
    const float* xr = x_in + (size_t)row * 6;
    float xv[6];
#pragma unroll
    for (int j = 0; j < 6; j++) xv[j] = xr[j];
    float acc[8];
#pragma unroll
    for (int i = 0; i < 8; i++) acc[i] = sb[cg + i];
#pragma unroll
    for (int j = 0; j < 6; j++)
#pragma unroll
        for (int i = 0; i < 8; i++) acc[i] += xv[j] * sw[j * 128 + cg + i];
    ushort4 h0, h1;
    h0.x = f2b(acc[0]); h0.y = f2b(acc[1]); h0.z = f2b(acc[2]); h0.w = f2b(acc[3]);
    h1.x = f2b(acc[4]); h1.y = f2b(acc[5]); h1.z = f2b(acc[6]); h1.w = f2b(acc[7]);
    uint4 pk;
    pk.x = (u32)h0.x | ((u32)h0.y << 16);
    pk.y = (u32)h0.z | ((u32)h0.w << 16);
    pk.z = (u32)h1.x | ((u32)h1.y << 16);
    pk.w = (u32)h1.z | ((u32)h1.w << 16);
    *(uint4*)(xout + (size_t)row * 128 + cg) = pk;
}

// ------------- weight pack: dst[n][k] = bf16(src[k][n]), per block i = blockIdx.z -------------
__global__ __launch_bounds__(256) void pack_w_kern(
    const float* __restrict__ src, u16* __restrict__ dst, int K)
{
    int i = blockIdx.z;
    src += (size_t)i * K * 128;
    dst += (size_t)i * K * 128;
    int idx = blockIdx.x * 256 + threadIdx.x;  // = n*K + k
    int n = idx / K;
    int k = idx % K;
    dst[idx] = f2b(src[(size_t)k * 128 + n]);
}

// ------------- rotation weight pack: WR1[n][k256] = [Are; -Aim]^T, WR2 = [Are; Aim]^T -------------
__global__ __launch_bounds__(256) void pack_rot_kern(
    const float* __restrict__ Are, const float* __restrict__ Aim,
    u16* __restrict__ WR1, u16* __restrict__ WR2)
{
    int i = blockIdx.z;
    const float* are = Are + (size_t)i * 16384;
    const float* aim = Aim + (size_t)i * 16384;
    int idx = blockIdx.x * 256 + threadIdx.x;  // 0..32767 = n*256 + k
    int n = idx >> 8;
    int k = idx & 255;
    float v1, v2;
    if (k < 128) { float a = are[(size_t)k * 128 + n]; v1 = a; v2 = a; }
    else         { float a = aim[(size_t)(k - 128) * 128 + n]; v1 = -a; v2 = a; }
    WR1[(size_t)i * 32768 + idx] = f2b(v1);
    WR2[(size_t)i * 32768 + idx] = f2b(v2);
}

// ------------- CSR build: histogram -> 3-phase parallel scan -> scatter idx -> gather vals -------------
__global__ __launch_bounds__(256) void hist_kern(const int* __restrict__ rows, int* count)
{
    int e = blockIdx.x * 256 + threadIdx.x;
    if (e < E_) atomicAdd(&count[rows[e]], 1);
}

// inclusive scan across a 256-thread block (4 waves, shfl-based)
__device__ __forceinline__ int block_incl_scan_256(int v, int t)
{
    __shared__ int wsum[4];
    int lane = t & 63;
    int wid = t >> 6;
    int x = v;
#pragma unroll
    for (int off = 1; off < 64; off <<= 1) {
        int y = __shfl_up(x, off);
        if (lane >= off) x += y;
    }
    if (lane == 63) wsum[wid] = x;
    __syncthreads();
    if (t == 0) {
        int s = 0;
#pragma unroll
        for (int i = 0; i < 4; i++) { int tm = wsum[i]; wsum[i] = s; s += tm; }
    }
    __syncthreads();
    return x + wsum[wid];
}

// phase 1: per-block exclusive scan of counts -> rowptr (partial), block totals
__global__ __launch_bounds__(256) void scan1_kern(
    const int* __restrict__ count, int* __restrict__ excl_out,
    int* __restrict__ blockTotals)
{
    int t = threadIdx.x;
    int g = blockIdx.x * 256 + t;
    int v = (g < N_) ? count[g] : 0;
    int incl = block_incl_scan_256(v, t);
    if (g < N_) excl_out[g] = incl - v;
    if (t == 255) blockTotals[blockIdx.x] = incl;
}

// phase 2: single-block scan of 157 block totals -> exclusive block offsets + grand total
__global__ __launch_bounds__(256) void scan2_kern(
    const int* __restrict__ blockTotals, int* __restrict__ blockOffs,
    int* __restrict__ totalOut)
{
    int t = threadIdx.x;
    int v = (t < NB_SCAN) ? blockTotals[t] : 0;
    int incl = block_incl_scan_256(v, t);
    if (t < NB_SCAN) blockOffs[t] = incl - v;
    if (t == 255) *totalOut = incl;   // = E_, written to rowptr[N_]
}

// phase 3: add block offsets; materialize rowptr + nextp cursors
__global__ __launch_bounds__(256) void scan3_kern(
    int* __restrict__ rowptr, int* __restrict__ nextp,
    const int* __restrict__ blockOffs)
{
    int t = threadIdx.x;
    int g = blockIdx.x * 256 + t;
    if (g >= N_) return;
    int v = rowptr[g] + blockOffs[blockIdx.x];
    rowptr[g] = v;
    nextp[g] = v;
}

// scatter only indices (2 scattered u32 writes per edge)
__global__ __launch_bounds__(256) void scatter_idx_kern(
    const int* __restrict__ rows, const int* __restrict__ cols,
    int* nextp, int* __restrict__ scols, int* __restrict__ sperm)
{
    int e = blockIdx.x * 256 + threadIdx.x;
    if (e >= E_) return;
    int r = rows[e];
    int pos = atomicAdd(&nextp[r], 1);
    scols[pos] = cols[e];
    sperm[pos] = e;
}

// gather values: coalesced writes, L2-cached random reads
__global__ __launch_bounds__(256) void gather_vals_kern(
    const int* __restrict__ sperm,
    const float* __restrict__ gvx, const float* __restrict__ gvy,
    float* __restrict__ svx, float* __restrict__ svy)
{
    int pos = blockIdx.x * 256 + threadIdx.x;
    if (pos >= E_) return;
    int e = sperm[pos];
#pragma unroll
    for (int b = 0; b < B_; b++) {
        svx[(size_t)b * E_ + pos] = gvx[(size_t)b * E_ + e];
        svy[(size_t)b * E_ + pos] = gvy[(size_t)b * E_ + e];
    }
}

// ------------- CSR dual spMM (all batches via z), bf16 packed out, edge-unrolled x2 -------------
__global__ __launch_bounds__(256) void spmm_csr_kern(
    const int* __restrict__ rowptr, const int* __restrict__ scols,
    const float* __restrict__ svx, const float* __restrict__ svy,
    const u16* __restrict__ xd, u16* __restrict__ gXY0, u16* __restrict__ gXY1)
{
    const size_t NZ = (size_t)N_ * 128;
    int z = blockIdx.z;
    const float* svx_b = svx + (size_t)z * E_;
    const float* svy_b = svy + (size_t)z * E_;
    const u16* xd_b = xd + (size_t)z * NZ;
    u16* base = (z < 2) ? (gXY0 + (size_t)z * 2 * NZ) : (gXY1 + (size_t)(z - 2) * 2 * NZ);
    u16* gXh = base;
    u16* gYh = base + NZ;

    int t = threadIdx.x;
    int r = blockIdx.x * 4 + (t >> 6);
    int c2 = (t & 63) * 2;
    int beg = rowptr[r], end = rowptr[r + 1];
    float ax0 = 0.f, ax1 = 0.f, ay0 = 0.f, ay1 = 0.f;
    int j = beg;
    for (; j + 1 < end; j += 2) {
        int ca = scols[j], cb = scols[j + 1];
        u32 xwa = *(const u32*)(xd_b + (size_t)ca * 128 + c2);
        u32 xwb = *(const u32*)(xd_b + (size_t)cb * 128 + c2);
        float vxa = svx_b[j], vya = svy_b[j];
        float vxb = svx_b[j + 1], vyb = svy_b[j + 1];
        float xa0 = b2f((u16)(xwa & 0xffffu)), xa1 = b2f((u16)(xwa >> 16));
        float xb0 = b2f((u16)(xwb & 0xffffu)), xb1 = b2f((u16)(xwb >> 16));
        ax0 += vxa * xa0; ax1 += vxa * xa1;
        ay0 += vya * xa0; ay1 += vya * xa1;
        ax0 += vxb * xb0; ax1 += vxb * xb1;
        ay0 += vyb * xb0; ay1 += vyb * xb1;
    }
    if (j < end) {
        int col = scols[j];
        u32 xw = *(const u32*)(xd_b + (size_t)col * 128 + c2);
        float x0 = b2f((u16)(xw & 0xffffu));
        float x1 = b2f((u16)(xw >> 16));
        float vx = svx_b[j], vy = svy_b[j];
        ax0 += vx * x0; ax1 += vx * x1;
        ay0 += vy * x0; ay1 += vy * x1;
    }
    u32 px = (u32)f2b(ax0) | ((u32)f2b(ax1) << 16);
    u32 py = (u32)f2b(ay0) | ((u32)f2b(ay1) << 16);
    *(u32*)(gXh + (size_t)r * 128 + c2) = px;
    *(u32*)(gYh + (size_t)r * 128 + c2) = py;
}

// ------------- spectral projection stage 1: MFMA over transposed LDS tiles -------------
__global__ __launch_bounds__(256) void spec_stage1_mfma_kern(
    const u16* __restrict__ x, const float* __restrict__ mass,
    const float* __restrict__ evecs, float* __restrict__ partials)
{
    __shared__ __align__(16) u16 sEVh[128][40];
    __shared__ __align__(16) u16 sEVl[128][40];
    __shared__ __align__(16) u16 sXM[128][40];
    int b = blockIdx.y;
    int pb = blockIdx.x;
    const u16* xb = x + (size_t)b * N_ * 128;
    const float* mb = mass + (size_t)b * N_;
    const float* eb = evecs + (size_t)b * N_ * 128;
    float* dst = partials + ((size_t)b * 128 + pb) * 16384;

    int t = threadIdx.x;
    int wv = t >> 6;
    int lane = t & 63;
    int quad = lane >> 4;
    int r16 = lane & 15;
    int kb = wv * 32;
    int kc = (t & 63) * 2;
    int nh = wv;

    f32x4 acc[2][8];
#pragma unroll
    for (int i = 0; i < 2; i++)
#pragma unroll
        for (int j = 0; j < 8; j++) acc[i][j] = (f32x4){0.f, 0.f, 0.f, 0.f};

    for (int ch = pb; ch < N_ / 32; ch += 128) {
        int nbase = ch * 32 + nh * 8;
        float4 m0 = *(const float4*)(mb + nbase);
        float4 m1 = *(const float4*)(mb + nbase + 4);
        float mm[8] = {m0.x, m0.y, m0.z, m0.w, m1.x, m1.y, m1.z, m1.w};
        u32 eh0[4], eh1[4], el0[4], el1[4], xq0[4], xq1[4];
#pragma unroll
        for (int jp = 0; jp < 4; jp++) {
            eh0[jp] = 0; eh1[jp] = 0; el0[jp] = 0;
            el1[jp] = 0; xq0[jp] = 0; xq1[jp] = 0;
        }
#pragma unroll
        for (int j = 0; j < 8; j++) {
            float2 e = *(const float2*)(eb + (size_t)(nbase + j) * 128 + kc);
            u32 xw = *(const u32*)(xb + (size_t)(nbase + j) * 128 + kc);
            u16 h0 = f2b(e.x);
            u16 h1 = f2b(e.y);
            u16 l0 = f2b(e.x - b2f(h0));
            u16 l1 = f2b(e.y - b2f(h1));
            u16 q0 = f2b(b2f((u16)(xw & 0xffffu)) * mm[j]);
            u16 q1 = f2b(b2f((u16)(xw >> 16)) * mm[j]);
            int sh = (j & 1) * 16;
            int jp = j >> 1;
            eh0[jp] |= ((u32)h0) << sh; eh1[jp] |= ((u32)h1) << sh;
            el0[jp] |= ((u32)l0) << sh; el1[jp] |= ((u32)l1) << sh;
            xq0[jp] |= ((u32)q0) << sh; xq1[jp] |= ((u32)q1) << sh;
        }
        __syncthreads();
        *(uint4*)&sEVh[kc][nh * 8]     = make_uint4(eh0[0], eh0[1], eh0[2], eh0[3]);
        *(uint4*)&sEVh[kc + 1][nh * 8] = make_uint4(eh1[0], eh1[1], eh1[2], eh1[3]);
        *(uint4*)&sEVl[kc][nh * 8]     = make_uint4(el0[0], el0[1], el0[2], el0[3]);
        *(uint4*)&sEVl[kc + 1][nh * 8] = make_uint4(el1[0], el1[1], el1[2], el1[3]);
        *(uint4*)&sXM[kc][nh * 8]      = make_uint4(xq0[0], xq0[1], xq0[2], xq0[3]);
        *(uint4*)&sXM[kc + 1][nh * 8]  = make_uint4(xq1[0], xq1[1], xq1[2], xq1[3]);
        __syncthreads();

        bf16x8 ah0 = *(const bf16x8*)&sEVh[kb + r16][quad * 8];
        bf16x8 ah1 = *(const bf16x8*)&sEVh[kb + 16 + r16][quad * 8];
        bf16x8 al0 = *(const bf16x8*)&sEVl[kb + r16][quad * 8];
        bf16x8 al1 = *(const bf16x8*)&sEVl[kb + 16 + r16][quad * 8];
#pragma unroll
        for (int nt = 0; nt < 8; nt++) {
            bf16x8 bx = *(const bf16x8*)&sXM[nt * 16 + r16][quad * 8];
            acc[0][nt] = __builtin_amdgcn_mfma_f32_16x16x32_bf16(ah0, bx, acc[0][nt], 0, 0, 0);
            acc[1][nt] = __builtin_amdgcn_mfma_f32_16x16x32_bf16(ah1, bx, acc[1][nt], 0, 0, 0);
            acc[0][nt] = __builtin_amdgcn_mfma_f32_16x16x32_bf16(al0, bx, acc[0][nt], 0, 0, 0);
            acc[1][nt] = __builtin_amdgcn_mfma_f32_16x16x32_bf16(al1, bx, acc[1][nt], 0, 0, 0);
        }
    }

#pragma unroll
    for (int mt = 0; mt < 2; mt++)
#pragma unroll
        for (int nt = 0; nt < 8; nt++)
#pragma unroll
            for (int reg = 0; reg < 4; reg++) {
                int kk = kb + mt * 16 + quad * 4 + reg;
                int cc = nt * 16 + r16;
                dst[(size_t)kk * 128 + cc] = acc[mt][nt][reg];
            }
}

// ------------- stage 2 + coefficients, TRANSPOSED bf16 out: ys_t[b][c][k] -------------
__global__ __launch_bounds__(128) void spec_stage2_coef_kern(
    const float* __restrict__ partials, const float* __restrict__ evals,
    const float* __restrict__ dt, u16* __restrict__ ys_t)
{
    int b = blockIdx.x >> 7;
    int k = blockIdx.x & 127;
    int c = threadIdx.x;
    const float* p = partials + (size_t)b * 128 * 16384 + (size_t)k * 128 + c;
    float s = 0.f;
#pragma unroll 8
    for (int pb = 0; pb < 128; pb++) s += p[(size_t)pb * 16384];
    float co = expf(-evals[b * 128 + k] * dt[c]);
    ys_t[((size_t)b * 128 + c) * 128 + k] = f2b(s * co);
}

// ------------- MFMA GEMM: out[m,0:128] = A[m,:KK] @ W (bf16 out); AF32 path for evecs ------
template <int KK, bool AF32>
__global__ __launch_bounds__(256) void mgemm_kern(
    const void* __restrict__ A0v,
    const u16* __restrict__ Wp, u16* __restrict__ outp,
    size_t aBatch, size_t wBatch, size_t oBatch)
{
    __shared__ u16 sA[64][72];
    __shared__ u16 sB[128][72];
    int z = blockIdx.z;
    const u16* Wb = Wp + wBatch * (size_t)z;
    size_t aOff = aBatch * (size_t)z;
    size_t oOff = oBatch * (size_t)z;

    int t = threadIdx.x;
    int m0 = blockIdx.x * 64;
    int wv = t >> 6;
    int lane = t & 63;
    int quad = lane >> 4;
    int r16 = lane & 15;
    int mw = (wv & 1) * 32;
    int nw = (wv >> 1) * 64;

    f32x4 acc[2][4];
#pragma unroll
    for (int i = 0; i < 2; i++)
#pragma unroll
        for (int j = 0; j < 4; j++) acc[i][j] = (f32x4){0.f, 0.f, 0.f, 0.f};

#pragma unroll 1
    for (int kt = 0; kt < KK / 64; kt++) {
        int kbase = kt * 64;
        __syncthreads();
        if (AF32) {
            const float* Af = (const float*)A0v + aOff;
#pragma unroll
            for (int p = 0; p < 4; p++) {
                int idx = p * 256 + t;
                int row = idx >> 4;
                int seg = idx & 15;
                float4 v = *(const float4*)(Af + (size_t)(m0 + row) * 128 + kbase + seg * 4);
                ushort4 h;
                h.x = f2b(v.x); h.y = f2b(v.y); h.z = f2b(v.z); h.w = f2b(v.w);
                *(ushort4*)&sA[row][seg * 4] = h;
            }
        } else {
            const u16* Ah = (const u16*)A0v + aOff;
#pragma unroll
            for (int p = 0; p < 2; p++) {
                int idx = p * 256 + t;
                int row = idx >> 3;
                int seg = idx & 7;
                *(uint4*)&sA[row][seg * 8] =
                    *(const uint4*)(Ah + (size_t)(m0 + row) * 128 + kbase + seg * 8);
            }
        }
        {
#pragma unroll
            for (int p = 0; p < 4; p++) {
                int idx = p * 256 + t;
                int n = idx >> 3;
                int seg = idx & 7;
                *(uint4*)&sB[n][seg * 8] =
                    *(const uint4*)(Wb + (size_t)n * KK + kbase + seg * 8);
            }
        }
        __syncthreads();

#pragma unroll
        for (int ks = 0; ks < 2; ks++) {
            int ko = ks * 32 + quad * 8;
            bf16x8 a0 = *(const bf16x8*)&sA[mw + r16][ko];
            bf16x8 a1 = *(const bf16x8*)&sA[mw + 16 + r16][ko];
            bf16x8 b0 = *(const bf16x8*)&sB[nw + r16][ko];
            bf16x8 b1 = *(const bf16x8*)&sB[nw + 16 + r16][ko];
            bf16x8 b2 = *(const bf16x8*)&sB[nw + 32 + r16][ko];
            bf16x8 b3 = *(const bf16x8*)&sB[nw + 48 + r16][ko];
            acc[0][0] = __builtin_amdgcn_mfma_f32_16x16x32_bf16(a0, b0, acc[0][0], 0, 0, 0);
            acc[0][1] = __builtin_amdgcn_mfma_f32_16x16x32_bf16(a0, b1, acc[0][1], 0, 0, 0);
            acc[0][2] = __builtin_amdgcn_mfma_f32_16x16x32_bf16(a0, b2, acc[0][2], 0, 0, 0);
            acc[0][3] = __builtin_amdgcn_mfma_f32_16x16x32_bf16(a0, b3, acc[0][3], 0, 0, 0);
            acc[1][0] = __builtin_amdgcn_mfma_f32_16x16x32_bf16(a1, b0, acc[1][0], 0, 0, 0);
            acc[1][1] = __builtin_amdgcn_mfma_f32_16x16x32_bf16(a1, b1, acc[1][1], 0, 0, 0);
            acc[1][2] = __builtin_amdgcn_mfma_f32_16x16x32_bf16(a1, b2, acc[1][2], 0, 0, 0);
            acc[1][3] = __builtin_amdgcn_mfma_f32_16x16x32_bf16(a1, b3, acc[1][3], 0, 0, 0);
        }
    }

#pragma unroll
    for (int nt = 0; nt < 4; nt++) {
        int col = nw + nt * 16 + r16;
#pragma unroll
        for (int mt = 0; mt < 2; mt++) {
#pragma unroll
            for (int reg = 0; reg < 4; reg++) {
                int row = m0 + mw + mt * 16 + quad * 4 + reg;
                outp[oOff + (size_t)row * 128 + col] = f2b(acc[mt][nt][reg]);
            }
        }
    }
}

// ------------- FUSED rotation + tanh + 3-layer MiniMLP (512 threads, all batches via z) -------------
// 8 waves: 2(M) x 4(N), each wave computes 32x32 per stage. Same 80 KB LDS as 256-thr version
// -> 2 blocks/CU x 8 waves = 4 waves/SIMD (double the latency-hiding pool).
__global__ __launch_bounds__(512) void mlp_rot_fused_kern(
    const u16* __restrict__ xg, const u16* __restrict__ xdg,
    const u16* __restrict__ gXY0, const u16* __restrict__ gXY1,
    const u16* __restrict__ WR1, const u16* __restrict__ WR2,
    const u16* __restrict__ W0, const u16* __restrict__ W1, const u16* __restrict__ W2,
    const float* __restrict__ b0, const float* __restrict__ b1, const float* __restrict__ b2,
    u16* __restrict__ outp)
{
    __shared__ u16 sGX[64][136];
    __shared__ u16 sGY[64][136];
    __shared__ u16 sB[128][72];
    __shared__ __align__(16) u16 sHbuf[9728];   // WR2 chunk view, then h1/h2 view
    __shared__ u16 sA[64][72];
#define HV(r, c) sHbuf[(r) * 152 + (c)]
#define WV(n, c) sHbuf[(n) * 72 + (c)]

    const size_t NZ = (size_t)N_ * 128;
    int z = blockIdx.z;                  // = batch
    const u16* gX = (z < 2) ? (gXY0 + (size_t)z * 2 * NZ) : (gXY1 + (size_t)(z - 2) * 2 * NZ);
    const u16* gY = gX + NZ;
    int m0n = blockIdx.x * 64;
    size_t growBase = ((size_t)z * N_ + m0n) * 128;

    int t = threadIdx.x;
    int wv = t >> 6;                     // 0..7
    int lane = t & 63;
    int quad = lane >> 4;
    int r16 = lane & 15;
    int mw = (wv & 1) * 32;              // 0 or 32
    int nw = (wv >> 1) * 32;             // 0,32,64,96

    // ---- stage gX, gY tiles (1024 uint4 each over 512 threads) ----
#pragma unroll
    for (int p = 0; p < 2; p++) {
        int idx = p * 512 + t;
        int row = idx >> 4;
        int seg = idx & 15;
        *(uint4*)&sGX[row][seg * 8] = *(const uint4*)(gX + (size_t)(m0n + row) * 128 + seg * 8);
        *(uint4*)&sGY[row][seg * 8] = *(const uint4*)(gY + (size_t)(m0n + row) * 128 + seg * 8);
    }

    f32x4 accRe[2][2], accIm[2][2];
#pragma unroll
    for (int i = 0; i < 2; i++)
#pragma unroll
        for (int j = 0; j < 2; j++) {
            accRe[i][j] = (f32x4){0.f, 0.f, 0.f, 0.f};
            accIm[i][j] = (f32x4){0.f, 0.f, 0.f, 0.f};
        }

    // ---- rotation: 4 x 64-k chunks; WR1 -> sB, WR2 -> sHbuf view ----
#pragma unroll 1
    for (int c = 0; c < 4; c++) {
        __syncthreads();   // c=0 also covers sGX/sGY staging
#pragma unroll
        for (int p = 0; p < 2; p++) {
            int idx = p * 512 + t;
            int n = idx >> 3;
            int seg = idx & 7;
            *(uint4*)&sB[n][seg * 8] = *(const uint4*)(WR1 + (size_t)n * 256 + c * 64 + seg * 8);
            *(uint4*)&WV(n, seg * 8) = *(const uint4*)(WR2 + (size_t)n * 256 + c * 64 + seg * 8);
        }
        __syncthreads();

        const u16 (*sRe)[136] = (c < 2) ? sGX : sGY;
        const u16 (*sIm)[136] = (c < 2) ? sGY : sGX;
        int kob = (c & 1) * 64;
#pragma unroll
        for (int ks = 0; ks < 2; ks++) {
            int ko = kob + ks * 32 + quad * 8;
            int kb = ks * 32 + quad * 8;
            bf16x8 aRe0 = *(const bf16x8*)&sRe[mw + r16][ko];
            bf16x8 aRe1 = *(const bf16x8*)&sRe[mw + 16 + r16][ko];
            bf16x8 aIm0 = *(const bf16x8*)&sIm[mw + r16][ko];
            bf16x8 aIm1 = *(const bf16x8*)&sIm[mw + 16 + r16][ko];
#pragma unroll
            for (int j = 0; j < 2; j++) {
                bf16x8 w1f = *(const bf16x8*)&sB[nw + 16 * j + r16][kb];
                bf16x8 w2f = *(const bf16x8*)&WV(nw + 16 * j + r16, kb);
                accRe[0][j] = __builtin_amdgcn_mfma_f32_16x16x32_bf16(aRe0, w1f, accRe[0][j], 0, 0, 0);
                accRe[1][j] = __builtin_amdgcn_mfma_f32_16x16x32_bf16(aRe1, w1f, accRe[1][j], 0, 0, 0);
                accIm[0][j] = __builtin_amdgcn_mfma_f32_16x16x32_bf16(aIm0, w2f, accIm[0][j], 0, 0, 0);
                accIm[1][j] = __builtin_amdgcn_mfma_f32_16x16x32_bf16(aIm1, w2f, accIm[1][j], 0, 0, 0);
            }
        }
    }

    // ---- tanh in place: gf -> sGX (each element owned by exactly one lane) ----
    __syncthreads();   // all fragment reads of sGX/sGY complete
#pragma unroll
    for (int nt = 0; nt < 2; nt++) {
        int col = nw + nt * 16 + r16;
#pragma unroll
        for (int mt = 0; mt < 2; mt++)
#pragma unroll
            for (int reg = 0; reg < 4; reg++) {
                int lrow = mw + mt * 16 + quad * 4 + reg;
                float gx = b2f(sGX[lrow][col]);
                float gy = b2f(sGY[lrow][col]);
                float v = tanhf(gx * accRe[mt][nt][reg] + gy * accIm[mt][nt][reg]);
                sGX[lrow][col] = f2b(v);
            }
    }

    // ---- MLP stage 0: K=384 over concat(x, xd, gf-from-LDS) ----
    f32x4 acc[2][2];
#pragma unroll
    for (int i = 0; i < 2; i++)
#pragma unroll
        for (int j = 0; j < 2; j++) acc[i][j] = (f32x4){0.f, 0.f, 0.f, 0.f};
#pragma unroll 1
    for (int kt = 0; kt < 6; kt++) {
        int kbase = kt * 64;
        int kloc = kbase & 127;
        __syncthreads();   // kt=0 covers tanh writes; also protects sA/sB reuse
        if (kt < 4) {
            const u16* Ap = (kt < 2) ? xg : xdg;
            {
                int row = t >> 3;        // 512 threads = 64 rows x 8 segs
                int seg = t & 7;
                *(uint4*)&sA[row][seg * 8] =
                    *(const uint4*)(Ap + growBase + (size_t)row * 128 + kloc + seg * 8);
            }
        }
#pragma unroll
        for (int p = 0; p < 2; p++) {
            int idx = p * 512 + t;
            int n = idx >> 3;
            int seg = idx & 7;
            *(uint4*)&sB[n][seg * 8] = *(const uint4*)(W0 + (size_t)n * 384 + kbase + seg * 8);
        }
        __syncthreads();
#pragma unroll
        for (int ks = 0; ks < 2; ks++) {
            int ko = ks * 32 + quad * 8;
            bf16x8 a0, a1;
            if (kt < 4) {
                a0 = *(const bf16x8*)&sA[mw + r16][ko];
                a1 = *(const bf16x8*)&sA[mw + 16 + r16][ko];
            } else {
                a0 = *(const bf16x8*)&sGX[mw + r16][kloc + ko];
                a1 = *(const bf16x8*)&sGX[mw + 16 + r16][kloc + ko];
            }
#pragma unroll
            for (int j = 0; j < 2; j++) {
                bf16x8 bj = *(const bf16x8*)&sB[nw + 16 * j + r16][ko];
                acc[0][j] = __builtin_amdgcn_mfma_f32_16x16x32_bf16(a0, bj, acc[0][j], 0, 0, 0);
                acc[1][j] = __builtin_amdgcn_mfma_f32_16x16x32_bf16(a1, bj, acc[1][j], 0, 0, 0);
            }
        }
    }
    // h1 -> sHbuf (bias + relu + bf16); WR2 chunks fully consumed
    __syncthreads();
#pragma unroll
    for (int nt = 0; nt < 2; nt++) {
        int col = nw + nt * 16 + r16;
        float bv = b0[col];
#pragma unroll
        for (int mt = 0; mt < 2; mt++)
#pragma unroll
            for (int reg = 0; reg < 4; reg++) {
                int rl = mw + mt * 16 + quad * 4 + reg;
                HV(rl, col) = f2b(fmaxf(acc[mt][nt][reg] + bv, 0.f));
            }
    }

    // ---- stage 1: h2 = relu(h1 @ W1 + b1) ----
#pragma unroll
    for (int i = 0; i < 2; i++)
#pragma unroll
        for (int j = 0; j < 2; j++) acc[i][j] = (f32x4){0.f, 0.f, 0.f, 0.f};
#pragma unroll 1
    for (int kt = 0; kt < 2; kt++) {
        int kbase = kt * 64;
        __syncthreads();   // kt=0 covers h1 writes
#pragma unroll
        for (int p = 0; p < 2; p++) {
            int idx = p * 512 + t;
            int n = idx >> 3;
            int seg = idx & 7;
            *(uint4*)&sB[n][seg * 8] = *(const uint4*)(W1 + (size_t)n * 128 + kbase + seg * 8);
        }
        __syncthreads();
#pragma unroll
        for (int ks = 0; ks < 2; ks++) {
            int ko = kbase + ks * 32 + quad * 8;
            int kb = ks * 32 + quad * 8;
            bf16x8 a0 = *(const bf16x8*)&HV(mw + r16, ko);
            bf16x8 a1 = *(const bf16x8*)&HV(mw + 16 + r16, ko);
#pragma unroll
            for (int j = 0; j < 2; j++) {
                bf16x8 bj = *(const bf16x8*)&sB[nw + 16 * j + r16][kb];
                acc[0][j] = __builtin_amdgcn_mfma_f32_16x16x32_bf16(a0, bj, acc[0][j], 0, 0, 0);
                acc[1][j] = __builtin_amdgcn_mfma_f32_16x16x32_bf16(a1, bj, acc[1][j], 0, 0, 0);
            }
        }
    }
    __syncthreads();   // all waves done reading h1
#pragma unroll
    for (int nt = 0; nt < 2; nt++) {
        int col = nw + nt * 16 + r16;
        float bv = b1[col];
#pragma unroll
        for (int mt = 0; mt < 2; mt++)
#pragma unroll
            for (int reg = 0; reg < 4; reg++) {
                int rl = mw + mt * 16 + quad * 4 + reg;
                HV(rl, col) = f2b(fmaxf(acc[mt][nt][reg] + bv, 0.f));
            }
    }

    // ---- stage 2: out = h2 @ W2 + b2 + resid(x) ----
#pragma unroll
    for (int i = 0; i < 2; i++)
#pragma unroll
        for (int j = 0; j < 2; j++) acc[i][j] = (f32x4){0.f, 0.f, 0.f, 0.f};
#pragma unroll 1
    for (int kt = 0; kt < 2; kt++) {
        int kbase = kt * 64;
        __syncthreads();   // kt=0 covers h2 writes
#pragma unroll
        for (int p = 0; p < 2; p++) {
            int idx = p * 512 + t;
            int n = idx >> 3;
            int seg = idx & 7;
            *(uint4*)&sB[n][seg * 8] = *(const uint4*)(W2 + (size_t)n * 128 + kbase + seg * 8);
        }
        __syncthreads();
#pragma unroll
        for (int ks = 0; ks < 2; ks++) {
            int ko = kbase + ks * 32 + quad * 8;
            int kb = ks * 32 + quad * 8;
            bf16x8 a0 = *(const bf16x8*)&HV(mw + r16, ko);
            bf16x8 a1 = *(const bf16x8*)&HV(mw + 16 + r16, ko);
#pragma unroll
            for (int j = 0; j < 2; j++) {
                bf16x8 bj = *(const bf16x8*)&sB[nw + 16 * j + r16][kb];
                acc[0][j] = __builtin_amdgcn_mfma_f32_16x16x32_bf16(a0, bj, acc[0][j], 0, 0, 0);
                acc[1][j] = __builtin_amdgcn_mfma_f32_16x16x32_bf16(a1, bj, acc[1][j], 0, 0, 0);
            }
        }
    }
#pragma unroll
    for (int nt = 0; nt < 2; nt++) {
        int col = nw + nt * 16 + r16;
        float bv = b2[col];
#pragma unroll
        for (int mt = 0; mt < 2; mt++)
#pragma unroll
            for (int reg = 0; reg < 4; reg++) {
                int row = mw + mt * 16 + quad * 4 + reg;
                float v = acc[mt][nt][reg] + bv + b2f(xg[growBase + (size_t)row * 128 + col]);
                outp[growBase + (size_t)row * 128 + col] = f2b(v);
            }
    }
#undef HV
#undef WV
}

// ------------- last linear: out[m,0:3] = x[m,:] @ w_last + b_last -------------
__global__ __launch_bounds__(256) void last_linear_kern(
    const u16* __restrict__ x, const float* __restrict__ w,
    const float* __restrict__ bias, float* __restrict__ outp, int M)
{
    __shared__ float sw[128 * 3];
    int t = threadIdx.x;
    for (int i = t; i < 384; i += 256) sw[i] = w[i];
    __syncthreads();
    int wave = t >> 6;
    int lane = t & 63;
    int row = blockIdx.x * 4 + wave;
    if (row >= M) return;
    const u16* xr = x + (size_t)row * 128;
    float p0 = 0.f, p1 = 0.f, p2 = 0.f;
#pragma unroll
    for (int h = 0; h < 2; h++) {
        int c = lane + h * 64;
        float xv = b2f(xr[c]);
        p0 += xv * sw[c * 3 + 0];
        p1 += xv * sw[c * 3 + 1];
        p2 += xv * sw[c * 3 + 2];
    }
#pragma unroll
    for (int off = 32; off > 0; off >>= 1) {
        p0 += __shfl_xor(p0, off);
        p1 += __shfl_xor(p1, off);
        p2 += __shfl_xor(p2, off);
    }
    if (lane == 0) {
        float* o = outp + (size_t)row * 3;
        o[0] = p0 + bias[0];
        o[1] = p1 + bias[1];
        o[2] = p2 + bias[2];
    }
}

extern "C" void kernel_launch(void* const* d_in, const int* in_sizes, int n_in,
                              void* d_out, int out_size, void* d_ws, size_t ws_size,
                              hipStream_t stream)
{
    const float* x_in    = (const float*)d_in[0];
    const float* mass    = (const float*)d_in[1];
    const float* evals   = (const float*)d_in[2];
    const float* evecs   = (const float*)d_in[3];
    const int*   rows    = (const int*)  d_in[4];
    const int*   cols    = (const int*)  d_in[5];
    const float* gvx     = (const float*)d_in[6];
    const float* gvy     = (const float*)d_in[7];
    const float* w_first = (const float*)d_in[8];
    const float* b_first = (const float*)d_in[9];
    const float* dtimes  = (const float*)d_in[10];
    const float* A_re    = (const float*)d_in[11];
    const float* A_im    = (const float*)d_in[12];
    const float* w0      = (const float*)d_in[13];
    const float* b0      = (const float*)d_in[14];
    const float* w1      = (const float*)d_in[15];
    const float* b1      = (const float*)d_in[16];
    const float* w2      = (const float*)d_in[17];
    const float* b2      = (const float*)d_in[18];
    const float* w_last  = (const float*)d_in[19];
    const float* b_last  = (const float*)d_in[20];
    float* outp = (float*)d_out;

    const size_t SZ = (size_t)B_ * N_ * 128;   // 20,480,000 elements
    const size_t NZ = (size_t)N_ * 128;        //  5,120,000 elements

    // workspace layout (~174 MB)
    u16* P0 = (u16*)d_ws;                      // 41 MB  (x ping-pong)
    u16* P1 = P0 + SZ;                         // 41 MB  (xd ping-pong)
    u16* GF = P1 + SZ;                         // 41 MB  (gX/gY slots 0-1)
    float* SC = (float*)(GF + SZ);             // 41 MB  partials / gX/gY slots 2-3 (disjoint lifetimes)
    u16* ys_t = (u16*)(SC + 8388608);          // 128 KB in SC tail (dead before spmm writes slots 2-3)
    u16* WP0 = (u16*)(SC + 2 * NZ);            // packed transposed bf16 weights
    u16* WP1 = WP0 + 4 * 49152;
    u16* WP2 = WP1 + 4 * 16384;
    u16* WR1 = WP2 + 4 * 16384;                // 4 x [128][256] rotation packs
    u16* WR2 = WR1 + 4 * 32768;
    int* rowptr = (int*)(WR2 + 4 * 32768);     // N+1 (padded to 40004)
    int* nextp  = rowptr + 40004;              // N (histogram counts, then cursors)
    int* scols  = nextp + N_;                  // E sorted cols
    float* svx  = (float*)(scols + E_);        // [B][E] sorted vals
    float* svy  = svx + (size_t)B_ * E_;

    u16* x  = P0;
    u16* xd = P1;
    const int M = B_ * N_;                     // 160000

    // --- CSR build (pattern shared across blocks & X/Y) ---
    int* bTot  = (int*)SC;          // NB_SCAN block totals (transient, pre-loop)
    int* bOff  = bTot + 512;
    int* sperm = bTot + 1024;       // E edge permutation (transient, pre-loop)
    hipMemsetAsync(nextp, 0, N_ * sizeof(int), stream);
    hist_kern<<<dim3((E_ + 255) / 256), 256, 0, stream>>>(rows, nextp);
    scan1_kern<<<dim3(NB_SCAN), 256, 0, stream>>>(nextp, rowptr, bTot);
    scan2_kern<<<dim3(1), 256, 0, stream>>>(bTot, bOff, rowptr + N_);
    scan3_kern<<<dim3(NB_SCAN), 256, 0, stream>>>(rowptr, nextp, bOff);
    scatter_idx_kern<<<dim3((E_ + 255) / 256), 256, 0, stream>>>(
        rows, cols, nextp, scols, sperm);
    gather_vals_kern<<<dim3((E_ + 255) / 256), 256, 0, stream>>>(
        sperm, gvx, gvy, svx, svy);

    // --- weight packing (once per launch) ---
    pack_w_kern<<<dim3(192, 1, 4), 256, 0, stream>>>(w0, WP0, 384);
    pack_w_kern<<<dim3(64, 1, 4), 256, 0, stream>>>(w1, WP1, 128);
    pack_w_kern<<<dim3(64, 1, 4), 256, 0, stream>>>(w2, WP2, 128);
    pack_rot_kern<<<dim3(128, 1, 4), 256, 0, stream>>>(A_re, A_im, WR1, WR2);

    first_linear_kern<<<dim3(M * 16 / 256), 256, 0, stream>>>(x_in, w_first, b_first, x, M);

    // gX/gY slots: z<2 in GF, z>=2 in SC (partials/ys_t dead by the time spmm writes)
    u16* GXY0 = GF;
    u16* GXY1 = (u16*)SC;

    for (int i = 0; i < 4; i++) {
        // --- spectral diffusion ---
        spec_stage1_mfma_kern<<<dim3(128, B_), 256, 0, stream>>>(x, mass, evecs, SC);
        spec_stage2_coef_kern<<<dim3(B_ * 128), 128, 0, stream>>>(
            SC, evals, dtimes + (size_t)i * 128, ys_t);
        mgemm_kern<128, true><<<dim3(N_ / 64, 1, B_), 256, 0, stream>>>(
            evecs, ys_t, xd, NZ, (size_t)128 * 128, NZ);
        // --- sparse gradients (all batches, one dispatch) ---
        spmm_csr_kern<<<dim3(N_ / 4, 1, B_), 256, 0, stream>>>(
            rowptr, scols, svx, svy, xd, GXY0, GXY1);
        // --- fused rotate+tanh+MLP+residual (all batches, one dispatch, 512 thr) ---
        mlp_rot_fused_kern<<<dim3(N_ / 64, 1, B_), 512, 0, stream>>>(
            x, xd, GXY0, GXY1,
            WR1 + (size_t)i * 32768, WR2 + (size_t)i * 32768,
            WP0 + (size_t)i * 49152, WP1 + (size_t)i * 16384, WP2 + (size_t)i * 16384,
            b0 + (size_t)i * 128, b1 + (size_t)i * 128, b2 + (size_t)i * 128,
            xd);
        u16* tmp = x; x = xd; xd = tmp;
    }

    last_linear_kern<<<dim3(M / 4), 256, 0, stream>>>(x, w_last, b_last, outp, M);
}